// Round 7
// baseline (308.234 us; speedup 1.0000x reference)
//
#include <hip/hip_runtime.h>
#include <hip/hip_bf16.h>

#define N_NODES 50000
#define N_EDGES 800000
#define DIM 128
#define NUM_GRAPHS 128
#define BN_EPS 1e-5f

constexpr int BK     = 7;                               // nodes-per-bucket log2
constexpr int NBUCK  = (N_NODES + 127) >> BK;           // 391
constexpr int TILE   = 4096;                            // edges per bscatter block
constexpr int NTILE  = (N_EDGES + TILE - 1) / TILE;     // 196

constexpr int XGRID  = 6250;                            // convert-x blocks
constexpr int WGRID  = 256;                             // convert-wt blocks

typedef __attribute__((ext_vector_type(8))) short short8;
typedef __attribute__((ext_vector_type(4))) float f32x4;

__device__ __forceinline__ unsigned short f2bu(float v)
{
    __hip_bfloat16 h = __float2bfloat16(v);
    unsigned short u;
    __builtin_memcpy(&u, &h, 2);
    return u;
}
__device__ __forceinline__ float lo2f(unsigned int v)
{
    return __builtin_bit_cast(float, v << 16);
}
__device__ __forceinline__ float hi2f(unsigned int v)
{
    return __builtin_bit_cast(float, v & 0xffff0000u);
}

// ---------------------------------------------------------------------------
// fused setup: convert x -> bf16, build transposed bf16 weights, zero bhist
// ---------------------------------------------------------------------------
__global__ __launch_bounds__(256)
void setup_kernel(const float* __restrict__ x, __hip_bfloat16* __restrict__ xb,
                  const float* __restrict__ w0, const float* __restrict__ w1,
                  const float* __restrict__ w2, const float* __restrict__ w3,
                  __hip_bfloat16* __restrict__ wt, int* __restrict__ bhist)
{
    int b = blockIdx.x;
    int t = threadIdx.x;
    if (b < XGRID) {
        size_t i = ((size_t)b * 256 + t) * 4;
        float4 v = *reinterpret_cast<const float4*>(x + i);
        uint2 o;
        o.x = (unsigned int)f2bu(v.x) | ((unsigned int)f2bu(v.y) << 16);
        o.y = (unsigned int)f2bu(v.z) | ((unsigned int)f2bu(v.w) << 16);
        *reinterpret_cast<uint2*>(reinterpret_cast<unsigned short*>(xb) + i) = o;
    } else if (b < XGRID + WGRID) {
        int o = (b - XGRID) * 256 + t;            // 65536
        int m = o >> 14, idx = o & 16383;
        const float* W = (m == 0) ? w0 : (m == 1) ? w1 : (m == 2) ? w2 : w3;
        int n = idx >> 7, k = idx & 127;
        wt[o] = __float2bfloat16(W[k * 128 + n]);
    } else {
        for (int i = t; i < NBUCK; i += 256) bhist[i] = 0;
    }
}

// ---------------------------------------------------------------------------
// Bucketed CSR build (round-6 design: single-writer output regions)
// ---------------------------------------------------------------------------
__global__ __launch_bounds__(256)
void bhist_kernel(const int* __restrict__ dst, int* __restrict__ bhist)
{
    __shared__ int h[NBUCK];
    int t = threadIdx.x;
    for (int i = t; i < NBUCK; i += 256) h[i] = 0;
    __syncthreads();
    int e0 = blockIdx.x * TILE;
    for (int i = t; i < TILE; i += 256) {
        int e = e0 + i;
        if (e < N_EDGES) atomicAdd(&h[dst[e] >> BK], 1);
    }
    __syncthreads();
    for (int i = t; i < NBUCK; i += 256)
        if (h[i]) atomicAdd(&bhist[i], h[i]);
}

__global__ __launch_bounds__(512)
void bscan_kernel(const int* __restrict__ bhist,
                  int* __restrict__ bofs, int* __restrict__ bcur)
{
    __shared__ int s[512];
    int t = threadIdx.x;
    int v = (t < NBUCK) ? bhist[t] : 0;
    s[t] = v;
    __syncthreads();
    for (int o = 1; o < 512; o <<= 1) {
        int a = (t >= o) ? s[t - o] : 0;
        __syncthreads();
        s[t] += a;
        __syncthreads();
    }
    if (t < NBUCK) {
        int ex = s[t] - v;
        bofs[t] = ex;
        bcur[t] = ex;
    }
    if (t == 0) bofs[NBUCK] = N_EDGES;
}

__global__ __launch_bounds__(512)
void bscatter_kernel(const int* __restrict__ src, const int* __restrict__ dst,
                     int* __restrict__ bcur, unsigned int* __restrict__ bedge)
{
    __shared__ int h[512];
    __shared__ int s[512];
    __shared__ int lofs[512];
    __shared__ int cur[512];
    __shared__ int gbase[512];
    __shared__ unsigned int stage[TILE];

    int t = threadIdx.x;
    h[t] = 0;
    __syncthreads();

    int e0 = blockIdx.x * TILE;
    for (int i = t; i < TILE; i += 512) {
        int e = e0 + i;
        if (e < N_EDGES) atomicAdd(&h[dst[e] >> BK], 1);
    }
    __syncthreads();

    int v = h[t];
    s[t] = v;
    __syncthreads();
    for (int o = 1; o < 512; o <<= 1) {
        int a = (t >= o) ? s[t - o] : 0;
        __syncthreads();
        s[t] += a;
        __syncthreads();
    }
    int excl = s[t] - v;
    lofs[t] = excl;
    cur[t]  = excl;
    if (t < NBUCK)
        gbase[t] = v ? atomicAdd(&bcur[t], v) : 0;
    __syncthreads();

    const int mtot = s[511];

    for (int i = t; i < TILE; i += 512) {
        int e = e0 + i;
        if (e < N_EDGES) {
            int d = dst[e];
            int b = d >> BK;
            int r = atomicAdd(&cur[b], 1);
            stage[r] = (unsigned int)src[e]
                     | ((unsigned int)(d & 127) << 16)
                     | ((unsigned int)b << 23);
        }
    }
    __syncthreads();

    for (int i = t; i < mtot; i += 512) {
        unsigned int w = stage[i];
        int b = (int)(w >> 23);
        bedge[gbase[b] + (i - lofs[b])] = w & 0x7fffffu;
    }
}

__global__ __launch_bounds__(256)
void bcsr_kernel(const unsigned int* __restrict__ bedge,
                 const int* __restrict__ bofs,
                 int* __restrict__ rowptr,
                 unsigned short* __restrict__ elist)
{
    __shared__ int h2[128];
    __shared__ int sc[128];
    __shared__ int cur[128];

    int b  = blockIdx.x;
    int t  = threadIdx.x;
    int e0 = bofs[b], e1 = bofs[b + 1];
    int m  = e1 - e0;

    if (t < 128) h2[t] = 0;
    __syncthreads();
    for (int i = t; i < m; i += 256)
        atomicAdd(&h2[(bedge[e0 + i] >> 16) & 127], 1);
    __syncthreads();

    if (t < 128) sc[t] = h2[t];
    __syncthreads();
    for (int o = 1; o < 128; o <<= 1) {
        int a = 0;
        if (t < 128 && t >= o) a = sc[t - o];
        __syncthreads();
        if (t < 128) sc[t] += a;
        __syncthreads();
    }
    if (t < 128) {
        int ex = sc[t] - h2[t];
        int node = (b << BK) + t;
        if (node < N_NODES) rowptr[node] = e0 + ex;
        cur[t] = ex;
    }
    if (b == 0 && t == 0) rowptr[N_NODES] = N_EDGES;
    __syncthreads();

    for (int i = t; i < m; i += 256) {
        unsigned int w = bedge[e0 + i];
        int n = (int)((w >> 16) & 127);
        int r = atomicAdd(&cur[n], 1);
        elist[e0 + r] = (unsigned short)(w & 0xffffu);
    }
}

// ---------------------------------------------------------------------------
// gather-aggregate (uint4 = 16B/lane). One WAVE per node:
//   lane = (edge-slot s = l>>4, chan-group g = l&15). One dwordx4 load
//   covers 4 edges per wave-instruction; unroll 2 -> 8 edges in flight.
//   Cross-slot reduce via __shfl_xor(16/32). Self term seeded in slot 0.
// ---------------------------------------------------------------------------
__device__ __forceinline__ void accum8(float* acc, uint4 v)
{
    acc[0] += lo2f(v.x); acc[1] += hi2f(v.x);
    acc[2] += lo2f(v.y); acc[3] += hi2f(v.y);
    acc[4] += lo2f(v.z); acc[5] += hi2f(v.z);
    acc[6] += lo2f(v.w); acc[7] += hi2f(v.w);
}

__global__ __launch_bounds__(256)
void gather_agg_kernel(const __hip_bfloat16* __restrict__ feat,
                       const int* __restrict__ rowptr,
                       const unsigned short* __restrict__ elist,
                       __hip_bfloat16* __restrict__ out)
{
    const int node = blockIdx.x * 4 + (threadIdx.x >> 6);
    const int l = threadIdx.x & 63;
    const int g = l & 15;               // uint4 index in row (8 channels)
    const int s = l >> 4;               // edge slot 0..3
    const uint4* F = reinterpret_cast<const uint4*>(feat);

    int p = rowptr[node];
    const int e = rowptr[node + 1];

    float acc[8] = {};
    if (s == 0)
        accum8(acc, F[(size_t)node * 16 + g]);

    for (; p + 8 <= e; p += 8) {
        int i0 = elist[p + s];
        int i1 = elist[p + 4 + s];
        uint4 v0 = F[(size_t)i0 * 16 + g];
        uint4 v1 = F[(size_t)i1 * 16 + g];
        accum8(acc, v0);
        accum8(acc, v1);
    }
    if (p + 4 <= e) {
        int i0 = elist[p + s];
        uint4 v0 = F[(size_t)i0 * 16 + g];
        accum8(acc, v0);
        p += 4;
    }
    if (p + s < e) {
        int i0 = elist[p + s];
        uint4 v0 = F[(size_t)i0 * 16 + g];
        accum8(acc, v0);
    }

    #pragma unroll
    for (int j = 0; j < 8; ++j) {
        acc[j] += __shfl_xor(acc[j], 16);
        acc[j] += __shfl_xor(acc[j], 32);
    }

    if (s == 0) {
        uint4 o;
        o.x = (unsigned int)f2bu(acc[0]) | ((unsigned int)f2bu(acc[1]) << 16);
        o.y = (unsigned int)f2bu(acc[2]) | ((unsigned int)f2bu(acc[3]) << 16);
        o.z = (unsigned int)f2bu(acc[4]) | ((unsigned int)f2bu(acc[5]) << 16);
        o.w = (unsigned int)f2bu(acc[6]) | ((unsigned int)f2bu(acc[7]) << 16);
        reinterpret_cast<uint4*>(out)[(size_t)node * 16 + g] = o;
    }
}

// ---------------------------------------------------------------------------
// Fused GIN MLP: out = relu( relu(BN(A @ W1 + b1)) @ W2 + b2 )
// MFMA 16x16x32, W in LDS, t1 in LDS (unchanged, verified round 4)
// ---------------------------------------------------------------------------
__global__ __launch_bounds__(256)
void mlp_kernel(const __hip_bfloat16* __restrict__ A,
                const __hip_bfloat16* __restrict__ W1t,
                const __hip_bfloat16* __restrict__ W2t,
                const float* __restrict__ b1,
                const float* __restrict__ bng, const float* __restrict__ bnb,
                const float* __restrict__ bnm, const float* __restrict__ bnv,
                const float* __restrict__ b2,
                __hip_bfloat16* __restrict__ out, int M)
{
    __shared__ __align__(16) short sW[128 * 136];   // 34.8 KB
    __shared__ __align__(16) short sT[64 * 136];    // 17.4 KB

    const int t    = threadIdx.x;
    const int w    = t >> 6;
    const int l    = t & 63;
    const int lr   = l & 15;
    const int lk   = (l >> 4) << 3;
    const int orow = (l >> 4) << 2;
    const int row0 = blockIdx.x * 64 + w * 16;

    const short* w1s = reinterpret_cast<const short*>(W1t);
    #pragma unroll
    for (int i = t; i < 2048; i += 256) {
        int r = i >> 4, c8 = (i & 15) << 3;
        *reinterpret_cast<short8*>(&sW[r * 136 + c8]) =
            *reinterpret_cast<const short8*>(&w1s[r * 128 + c8]);
    }

    float sc1[8], sh1[8];
    #pragma unroll
    for (int ct = 0; ct < 8; ++ct) {
        int c = ct * 16 + lr;
        float s = bng[c] * rsqrtf(bnv[c] + BN_EPS);
        sc1[ct] = s;
        sh1[ct] = (b1[c] - bnm[c]) * s + bnb[c];
    }

    const short* Ab = reinterpret_cast<const short*>(A);
    const int arow = row0 + lr;
    short8 af[4];
    #pragma unroll
    for (int ks = 0; ks < 4; ++ks) {
        short8 z = {};
        af[ks] = (arow < M)
            ? *reinterpret_cast<const short8*>(Ab + (size_t)arow * DIM + ks * 32 + lk)
            : z;
    }

    __syncthreads();

    f32x4 acc[8] = {};
    #pragma unroll
    for (int ks = 0; ks < 4; ++ks) {
        #pragma unroll
        for (int ct = 0; ct < 8; ++ct) {
            short8 bf = *reinterpret_cast<const short8*>(
                &sW[(ct * 16 + lr) * 136 + ks * 32 + lk]);
            acc[ct] = __builtin_amdgcn_mfma_f32_16x16x32_bf16(af[ks], bf, acc[ct], 0, 0, 0);
        }
    }

    #pragma unroll
    for (int ct = 0; ct < 8; ++ct) {
        #pragma unroll
        for (int q = 0; q < 4; ++q) {
            float v = fmaxf(acc[ct][q] * sc1[ct] + sh1[ct], 0.f);
            sT[(w * 16 + orow + q) * 136 + ct * 16 + lr] = (short)f2bu(v);
        }
    }

    __syncthreads();
    const short* w2s = reinterpret_cast<const short*>(W2t);
    #pragma unroll
    for (int i = t; i < 2048; i += 256) {
        int r = i >> 4, c8 = (i & 15) << 3;
        *reinterpret_cast<short8*>(&sW[r * 136 + c8]) =
            *reinterpret_cast<const short8*>(&w2s[r * 128 + c8]);
    }
    __syncthreads();

    f32x4 acc2[8] = {};
    #pragma unroll
    for (int ks = 0; ks < 4; ++ks) {
        short8 tf = *reinterpret_cast<const short8*>(
            &sT[(w * 16 + lr) * 136 + ks * 32 + lk]);
        #pragma unroll
        for (int ct = 0; ct < 8; ++ct) {
            short8 bf = *reinterpret_cast<const short8*>(
                &sW[(ct * 16 + lr) * 136 + ks * 32 + lk]);
            acc2[ct] = __builtin_amdgcn_mfma_f32_16x16x32_bf16(tf, bf, acc2[ct], 0, 0, 0);
        }
    }

    #pragma unroll
    for (int ct = 0; ct < 8; ++ct) {
        float bi = b2[ct * 16 + lr];
        #pragma unroll
        for (int q = 0; q < 4; ++q) {
            int r = row0 + orow + q;
            if (r < M) {
                float v = fmaxf(acc2[ct][q] + bi, 0.f);
                out[(size_t)r * DIM + ct * 16 + lr] = __float2bfloat16(v);
            }
        }
    }
}

// ---------------------------------------------------------------------------
// global_add_pool over sorted batch ids (bf16 in, f32 out)
// ---------------------------------------------------------------------------
__global__ __launch_bounds__(256)
void pool_kernel(const __hip_bfloat16* __restrict__ h,
                 const int* __restrict__ batch,
                 float* __restrict__ G,
                 int n_nodes)
{
    const int g = blockIdx.x;
    int lo = 0, hi = n_nodes;
    while (lo < hi) { int mid = (lo + hi) >> 1; if (batch[mid] < g) lo = mid + 1; else hi = mid; }
    const int start = lo;
    hi = n_nodes;
    while (lo < hi) { int mid = (lo + hi) >> 1; if (batch[mid] < g + 1) lo = mid + 1; else hi = mid; }
    const int end = lo;

    const int t  = threadIdx.x;
    const int cu = t & 63;
    const int rp = t >> 6;
    const unsigned int* F = reinterpret_cast<const unsigned int*>(h);
    float a0 = 0.f, a1 = 0.f;
    for (int r = start + rp; r < end; r += 4) {
        unsigned int v = F[(size_t)r * 64 + cu];
        a0 += lo2f(v); a1 += hi2f(v);
    }
    __shared__ float s0[256], s1[256];
    s0[t] = a0; s1[t] = a1;
    __syncthreads();
    if (t < 64) {
        float r0 = s0[t] + s0[t + 64] + s0[t + 128] + s0[t + 192];
        float r1 = s1[t] + s1[t + 64] + s1[t + 128] + s1[t + 192];
        G[g * DIM + cu * 2]     = r0;
        G[g * DIM + cu * 2 + 1] = r1;
    }
}

// ---------------------------------------------------------------------------
// fused head: out = relu(G @ lin1 + b1) @ lin2 + b2, one block, G2 in LDS
// ---------------------------------------------------------------------------
__global__ __launch_bounds__(1024)
void head_kernel(const float* __restrict__ G,
                 const float* __restrict__ w1, const float* __restrict__ b1f,
                 const float* __restrict__ w2, const float* __restrict__ b2f,
                 float* __restrict__ out)
{
    __shared__ float sG2[NUM_GRAPHS * DIM];      // 64 KB
    const int t = threadIdx.x;
    #pragma unroll
    for (int o = t; o < NUM_GRAPHS * DIM; o += 1024) {
        int r = o >> 7, c = o & 127;
        float a = b1f[c];
        #pragma unroll 4
        for (int k = 0; k < DIM; ++k)
            a = fmaf(G[r * DIM + k], w1[k * DIM + c], a);
        sG2[o] = fmaxf(a, 0.f);
    }
    __syncthreads();
    if (t < NUM_GRAPHS * 2) {
        int r = t >> 1, c = t & 1;
        float a = b2f[c];
        #pragma unroll 4
        for (int k = 0; k < DIM; ++k)
            a = fmaf(sG2[r * DIM + k], w2[k * 2 + c], a);
        out[t] = a;
    }
}

// ---------------------------------------------------------------------------
extern "C" void kernel_launch(void* const* d_in, const int* in_sizes, int n_in,
                              void* d_out, int out_size, void* d_ws, size_t ws_size,
                              hipStream_t stream)
{
    const float* x    = (const float*)d_in[0];
    const int*   ei   = (const int*)d_in[1];
    const int*   src  = ei;
    const int*   dst  = ei + N_EDGES;
    const int*   batch= (const int*)d_in[2];
    const float* w1_1 = (const float*)d_in[3];
    const float* b1_1 = (const float*)d_in[4];
    const float* bn1g = (const float*)d_in[5];
    const float* bn1b = (const float*)d_in[6];
    const float* bn1m = (const float*)d_in[7];
    const float* bn1v = (const float*)d_in[8];
    const float* w1_2 = (const float*)d_in[9];
    const float* b1_2 = (const float*)d_in[10];
    const float* w2_1 = (const float*)d_in[11];
    const float* b2_1 = (const float*)d_in[12];
    const float* bn2g = (const float*)d_in[13];
    const float* bn2b = (const float*)d_in[14];
    const float* bn2m = (const float*)d_in[15];
    const float* bn2v = (const float*)d_in[16];
    const float* w2_2 = (const float*)d_in[17];
    const float* b2_2 = (const float*)d_in[18];
    const float* lin1w= (const float*)d_in[19];
    const float* lin1b= (const float*)d_in[20];
    const float* lin2w= (const float*)d_in[21];
    const float* lin2b= (const float*)d_in[22];

    const size_t NBE = (size_t)N_NODES * DIM;      // 6.4M
    __hip_bfloat16* xb = (__hip_bfloat16*)d_ws;    // NBE bf16
    __hip_bfloat16* Ab = xb + NBE;                 // NBE bf16 (agg)
    __hip_bfloat16* Hb = Ab + NBE;                 // NBE bf16 (mlp out)
    __hip_bfloat16* Wt = Hb + NBE;                 // 4 * 16384 bf16
    float* G  = (float*)(Wt + 4 * 16384);
    int* rowptr = (int*)(G + NUM_GRAPHS * DIM);    // N_NODES+1
    int* bhist  = rowptr + N_NODES + 2;            // NBUCK
    int* bofs   = bhist + NBUCK;                   // NBUCK+1
    int* bcur   = bofs + NBUCK + 1;                // NBUCK
    unsigned int* bedge = (unsigned int*)(bcur + NBUCK + 1);     // N_EDGES
    unsigned short* elist = (unsigned short*)(bedge + N_EDGES);  // N_EDGES

    const int gather_grid = N_NODES / 4;               // 12500
    const int mlp_grid    = (N_NODES + 63) / 64;       // 782

    // ---- fused setup + bucketed CSR build ----
    setup_kernel<<<XGRID + WGRID + 1, 256, 0, stream>>>(
        x, xb, w1_1, w1_2, w2_1, w2_2, Wt, bhist);
    bhist_kernel<<<NTILE, 256, 0, stream>>>(dst, bhist);
    bscan_kernel<<<1, 512, 0, stream>>>(bhist, bofs, bcur);
    bscatter_kernel<<<NTILE, 512, 0, stream>>>(src, dst, bcur, bedge);
    bcsr_kernel<<<NBUCK, 256, 0, stream>>>(bedge, bofs, rowptr, elist);

    // ---- conv1 ----
    gather_agg_kernel<<<gather_grid, 256, 0, stream>>>(xb, rowptr, elist, Ab);
    mlp_kernel<<<mlp_grid, 256, 0, stream>>>(
        Ab, Wt, Wt + 16384, b1_1, bn1g, bn1b, bn1m, bn1v, b1_2, Hb, N_NODES);

    // ---- conv2 ----
    gather_agg_kernel<<<gather_grid, 256, 0, stream>>>(Hb, rowptr, elist, Ab);
    mlp_kernel<<<mlp_grid, 256, 0, stream>>>(
        Ab, Wt + 2 * 16384, Wt + 3 * 16384, b2_1, bn2g, bn2b, bn2m, bn2v, b2_2, Hb, N_NODES);

    // ---- pool + fused head ----
    pool_kernel<<<NUM_GRAPHS, 256, 0, stream>>>(Hb, batch, G, N_NODES);
    head_kernel<<<1, 1024, 0, stream>>>(G, lin1w, lin1b, lin2w, lin2b, (float*)d_out);
}

// Round 8
// 203.632 us; speedup vs baseline: 1.5137x; 1.5137x over previous
//
#include <hip/hip_runtime.h>
#include <hip/hip_bf16.h>

#define N_NODES 50000
#define N_EDGES 800000
#define DIM 128
#define NUM_GRAPHS 128
#define BN_EPS 1e-5f

constexpr int BK     = 7;                               // nodes-per-bucket log2
constexpr int NBUCK  = (N_NODES + 127) >> BK;           // 391
constexpr int TILE   = 4096;                            // edges per bscatter block
constexpr int NTILE  = (N_EDGES + TILE - 1) / TILE;     // 196

constexpr int XGRID  = 6250;                            // convert-x blocks
constexpr int WGRID  = 256;                             // convert-wt blocks

typedef __attribute__((ext_vector_type(8))) short short8;
typedef __attribute__((ext_vector_type(4))) float f32x4;

__device__ __forceinline__ unsigned short f2bu(float v)
{
    __hip_bfloat16 h = __float2bfloat16(v);
    unsigned short u;
    __builtin_memcpy(&u, &h, 2);
    return u;
}
__device__ __forceinline__ float lo2f(unsigned int v)
{
    return __builtin_bit_cast(float, v << 16);
}
__device__ __forceinline__ float hi2f(unsigned int v)
{
    return __builtin_bit_cast(float, v & 0xffff0000u);
}

// ---------------------------------------------------------------------------
// fused setup: convert x -> bf16, build transposed bf16 weights, zero bhist
// ---------------------------------------------------------------------------
__global__ __launch_bounds__(256)
void setup_kernel(const float* __restrict__ x, __hip_bfloat16* __restrict__ xb,
                  const float* __restrict__ w0, const float* __restrict__ w1,
                  const float* __restrict__ w2, const float* __restrict__ w3,
                  __hip_bfloat16* __restrict__ wt, int* __restrict__ bhist)
{
    int b = blockIdx.x;
    int t = threadIdx.x;
    if (b < XGRID) {
        size_t i = ((size_t)b * 256 + t) * 4;
        float4 v = *reinterpret_cast<const float4*>(x + i);
        uint2 o;
        o.x = (unsigned int)f2bu(v.x) | ((unsigned int)f2bu(v.y) << 16);
        o.y = (unsigned int)f2bu(v.z) | ((unsigned int)f2bu(v.w) << 16);
        *reinterpret_cast<uint2*>(reinterpret_cast<unsigned short*>(xb) + i) = o;
    } else if (b < XGRID + WGRID) {
        int o = (b - XGRID) * 256 + t;            // 65536
        int m = o >> 14, idx = o & 16383;
        const float* W = (m == 0) ? w0 : (m == 1) ? w1 : (m == 2) ? w2 : w3;
        int n = idx >> 7, k = idx & 127;
        wt[o] = __float2bfloat16(W[k * 128 + n]);
    } else {
        for (int i = t; i < NBUCK; i += 256) bhist[i] = 0;
    }
}

// ---------------------------------------------------------------------------
// Bucketed CSR build (single-writer output regions; verified round 6)
// ---------------------------------------------------------------------------
__global__ __launch_bounds__(256)
void bhist_kernel(const int* __restrict__ dst, int* __restrict__ bhist)
{
    __shared__ int h[NBUCK];
    int t = threadIdx.x;
    for (int i = t; i < NBUCK; i += 256) h[i] = 0;
    __syncthreads();
    int e0 = blockIdx.x * TILE;
    for (int i = t; i < TILE; i += 256) {
        int e = e0 + i;
        if (e < N_EDGES) atomicAdd(&h[dst[e] >> BK], 1);
    }
    __syncthreads();
    for (int i = t; i < NBUCK; i += 256)
        if (h[i]) atomicAdd(&bhist[i], h[i]);
}

__global__ __launch_bounds__(512)
void bscan_kernel(const int* __restrict__ bhist,
                  int* __restrict__ bofs, int* __restrict__ bcur)
{
    __shared__ int s[512];
    int t = threadIdx.x;
    int v = (t < NBUCK) ? bhist[t] : 0;
    s[t] = v;
    __syncthreads();
    for (int o = 1; o < 512; o <<= 1) {
        int a = (t >= o) ? s[t - o] : 0;
        __syncthreads();
        s[t] += a;
        __syncthreads();
    }
    if (t < NBUCK) {
        int ex = s[t] - v;
        bofs[t] = ex;
        bcur[t] = ex;
    }
    if (t == 0) bofs[NBUCK] = N_EDGES;
}

__global__ __launch_bounds__(512)
void bscatter_kernel(const int* __restrict__ src, const int* __restrict__ dst,
                     int* __restrict__ bcur, unsigned int* __restrict__ bedge)
{
    __shared__ int h[512];
    __shared__ int s[512];
    __shared__ int lofs[512];
    __shared__ int cur[512];
    __shared__ int gbase[512];
    __shared__ unsigned int stage[TILE];

    int t = threadIdx.x;
    h[t] = 0;
    __syncthreads();

    int e0 = blockIdx.x * TILE;
    for (int i = t; i < TILE; i += 512) {
        int e = e0 + i;
        if (e < N_EDGES) atomicAdd(&h[dst[e] >> BK], 1);
    }
    __syncthreads();

    int v = h[t];
    s[t] = v;
    __syncthreads();
    for (int o = 1; o < 512; o <<= 1) {
        int a = (t >= o) ? s[t - o] : 0;
        __syncthreads();
        s[t] += a;
        __syncthreads();
    }
    int excl = s[t] - v;
    lofs[t] = excl;
    cur[t]  = excl;
    if (t < NBUCK)
        gbase[t] = v ? atomicAdd(&bcur[t], v) : 0;
    __syncthreads();

    const int mtot = s[511];

    for (int i = t; i < TILE; i += 512) {
        int e = e0 + i;
        if (e < N_EDGES) {
            int d = dst[e];
            int b = d >> BK;
            int r = atomicAdd(&cur[b], 1);
            stage[r] = (unsigned int)src[e]
                     | ((unsigned int)(d & 127) << 16)
                     | ((unsigned int)b << 23);
        }
    }
    __syncthreads();

    for (int i = t; i < mtot; i += 512) {
        unsigned int w = stage[i];
        int b = (int)(w >> 23);
        bedge[gbase[b] + (i - lofs[b])] = w & 0x7fffffu;
    }
}

__global__ __launch_bounds__(256)
void bcsr_kernel(const unsigned int* __restrict__ bedge,
                 const int* __restrict__ bofs,
                 int* __restrict__ rowptr,
                 unsigned short* __restrict__ elist)
{
    __shared__ int h2[128];
    __shared__ int sc[128];
    __shared__ int cur[128];

    int b  = blockIdx.x;
    int t  = threadIdx.x;
    int e0 = bofs[b], e1 = bofs[b + 1];
    int m  = e1 - e0;

    if (t < 128) h2[t] = 0;
    __syncthreads();
    for (int i = t; i < m; i += 256)
        atomicAdd(&h2[(bedge[e0 + i] >> 16) & 127], 1);
    __syncthreads();

    if (t < 128) sc[t] = h2[t];
    __syncthreads();
    for (int o = 1; o < 128; o <<= 1) {
        int a = 0;
        if (t < 128 && t >= o) a = sc[t - o];
        __syncthreads();
        if (t < 128) sc[t] += a;
        __syncthreads();
    }
    if (t < 128) {
        int ex = sc[t] - h2[t];
        int node = (b << BK) + t;
        if (node < N_NODES) rowptr[node] = e0 + ex;
        cur[t] = ex;
    }
    if (b == 0 && t == 0) rowptr[N_NODES] = N_EDGES;
    __syncthreads();

    for (int i = t; i < m; i += 256) {
        unsigned int w = bedge[e0 + i];
        int n = (int)((w >> 16) & 127);
        int r = atomicAdd(&cur[n], 1);
        elist[e0 + r] = (unsigned short)(w & 0xffffu);
    }
}

// ---------------------------------------------------------------------------
// gather-aggregate (uint4 = 16B/lane). One WAVE per node (verified round 7):
//   lane = (edge-slot s = l>>4, chan-group g = l&15); 4 edges per wave-load,
//   unroll 2; cross-slot reduce via __shfl_xor(16/32); self term in slot 0.
// ---------------------------------------------------------------------------
__device__ __forceinline__ void accum8(float* acc, uint4 v)
{
    acc[0] += lo2f(v.x); acc[1] += hi2f(v.x);
    acc[2] += lo2f(v.y); acc[3] += hi2f(v.y);
    acc[4] += lo2f(v.z); acc[5] += hi2f(v.z);
    acc[6] += lo2f(v.w); acc[7] += hi2f(v.w);
}

__global__ __launch_bounds__(256)
void gather_agg_kernel(const __hip_bfloat16* __restrict__ feat,
                       const int* __restrict__ rowptr,
                       const unsigned short* __restrict__ elist,
                       __hip_bfloat16* __restrict__ out)
{
    const int node = blockIdx.x * 4 + (threadIdx.x >> 6);
    const int l = threadIdx.x & 63;
    const int g = l & 15;               // uint4 index in row (8 channels)
    const int s = l >> 4;               // edge slot 0..3
    const uint4* F = reinterpret_cast<const uint4*>(feat);

    int p = rowptr[node];
    const int e = rowptr[node + 1];

    float acc[8] = {};
    if (s == 0)
        accum8(acc, F[(size_t)node * 16 + g]);

    for (; p + 8 <= e; p += 8) {
        int i0 = elist[p + s];
        int i1 = elist[p + 4 + s];
        uint4 v0 = F[(size_t)i0 * 16 + g];
        uint4 v1 = F[(size_t)i1 * 16 + g];
        accum8(acc, v0);
        accum8(acc, v1);
    }
    if (p + 4 <= e) {
        int i0 = elist[p + s];
        uint4 v0 = F[(size_t)i0 * 16 + g];
        accum8(acc, v0);
        p += 4;
    }
    if (p + s < e) {
        int i0 = elist[p + s];
        uint4 v0 = F[(size_t)i0 * 16 + g];
        accum8(acc, v0);
    }

    #pragma unroll
    for (int j = 0; j < 8; ++j) {
        acc[j] += __shfl_xor(acc[j], 16);
        acc[j] += __shfl_xor(acc[j], 32);
    }

    if (s == 0) {
        uint4 o;
        o.x = (unsigned int)f2bu(acc[0]) | ((unsigned int)f2bu(acc[1]) << 16);
        o.y = (unsigned int)f2bu(acc[2]) | ((unsigned int)f2bu(acc[3]) << 16);
        o.z = (unsigned int)f2bu(acc[4]) | ((unsigned int)f2bu(acc[5]) << 16);
        o.w = (unsigned int)f2bu(acc[6]) | ((unsigned int)f2bu(acc[7]) << 16);
        reinterpret_cast<uint4*>(out)[(size_t)node * 16 + g] = o;
    }
}

// ---------------------------------------------------------------------------
// Fused GIN MLP: out = relu( relu(BN(A @ W1 + b1)) @ W2 + b2 )
// MFMA 16x16x32, W in LDS, t1 in LDS (unchanged, verified round 4)
// ---------------------------------------------------------------------------
__global__ __launch_bounds__(256)
void mlp_kernel(const __hip_bfloat16* __restrict__ A,
                const __hip_bfloat16* __restrict__ W1t,
                const __hip_bfloat16* __restrict__ W2t,
                const float* __restrict__ b1,
                const float* __restrict__ bng, const float* __restrict__ bnb,
                const float* __restrict__ bnm, const float* __restrict__ bnv,
                const float* __restrict__ b2,
                __hip_bfloat16* __restrict__ out, int M)
{
    __shared__ __align__(16) short sW[128 * 136];   // 34.8 KB
    __shared__ __align__(16) short sT[64 * 136];    // 17.4 KB

    const int t    = threadIdx.x;
    const int w    = t >> 6;
    const int l    = t & 63;
    const int lr   = l & 15;
    const int lk   = (l >> 4) << 3;
    const int orow = (l >> 4) << 2;
    const int row0 = blockIdx.x * 64 + w * 16;

    const short* w1s = reinterpret_cast<const short*>(W1t);
    #pragma unroll
    for (int i = t; i < 2048; i += 256) {
        int r = i >> 4, c8 = (i & 15) << 3;
        *reinterpret_cast<short8*>(&sW[r * 136 + c8]) =
            *reinterpret_cast<const short8*>(&w1s[r * 128 + c8]);
    }

    float sc1[8], sh1[8];
    #pragma unroll
    for (int ct = 0; ct < 8; ++ct) {
        int c = ct * 16 + lr;
        float s = bng[c] * rsqrtf(bnv[c] + BN_EPS);
        sc1[ct] = s;
        sh1[ct] = (b1[c] - bnm[c]) * s + bnb[c];
    }

    const short* Ab = reinterpret_cast<const short*>(A);
    const int arow = row0 + lr;
    short8 af[4];
    #pragma unroll
    for (int ks = 0; ks < 4; ++ks) {
        short8 z = {};
        af[ks] = (arow < M)
            ? *reinterpret_cast<const short8*>(Ab + (size_t)arow * DIM + ks * 32 + lk)
            : z;
    }

    __syncthreads();

    f32x4 acc[8] = {};
    #pragma unroll
    for (int ks = 0; ks < 4; ++ks) {
        #pragma unroll
        for (int ct = 0; ct < 8; ++ct) {
            short8 bf = *reinterpret_cast<const short8*>(
                &sW[(ct * 16 + lr) * 136 + ks * 32 + lk]);
            acc[ct] = __builtin_amdgcn_mfma_f32_16x16x32_bf16(af[ks], bf, acc[ct], 0, 0, 0);
        }
    }

    #pragma unroll
    for (int ct = 0; ct < 8; ++ct) {
        #pragma unroll
        for (int q = 0; q < 4; ++q) {
            float v = fmaxf(acc[ct][q] * sc1[ct] + sh1[ct], 0.f);
            sT[(w * 16 + orow + q) * 136 + ct * 16 + lr] = (short)f2bu(v);
        }
    }

    __syncthreads();
    const short* w2s = reinterpret_cast<const short*>(W2t);
    #pragma unroll
    for (int i = t; i < 2048; i += 256) {
        int r = i >> 4, c8 = (i & 15) << 3;
        *reinterpret_cast<short8*>(&sW[r * 136 + c8]) =
            *reinterpret_cast<const short8*>(&w2s[r * 128 + c8]);
    }
    __syncthreads();

    f32x4 acc2[8] = {};
    #pragma unroll
    for (int ks = 0; ks < 4; ++ks) {
        short8 tf = *reinterpret_cast<const short8*>(
            &sT[(w * 16 + lr) * 136 + ks * 32 + lk]);
        #pragma unroll
        for (int ct = 0; ct < 8; ++ct) {
            short8 bf = *reinterpret_cast<const short8*>(
                &sW[(ct * 16 + lr) * 136 + ks * 32 + lk]);
            acc2[ct] = __builtin_amdgcn_mfma_f32_16x16x32_bf16(tf, bf, acc2[ct], 0, 0, 0);
        }
    }

    #pragma unroll
    for (int ct = 0; ct < 8; ++ct) {
        float bi = b2[ct * 16 + lr];
        #pragma unroll
        for (int q = 0; q < 4; ++q) {
            int r = row0 + orow + q;
            if (r < M) {
                float v = fmaxf(acc2[ct][q] + bi, 0.f);
                out[(size_t)r * DIM + ct * 16 + lr] = __float2bfloat16(v);
            }
        }
    }
}

// ---------------------------------------------------------------------------
// global_add_pool over sorted batch ids (bf16 in, f32 out)
// ---------------------------------------------------------------------------
__global__ __launch_bounds__(256)
void pool_kernel(const __hip_bfloat16* __restrict__ h,
                 const int* __restrict__ batch,
                 float* __restrict__ G,
                 int n_nodes)
{
    const int g = blockIdx.x;
    int lo = 0, hi = n_nodes;
    while (lo < hi) { int mid = (lo + hi) >> 1; if (batch[mid] < g) lo = mid + 1; else hi = mid; }
    const int start = lo;
    hi = n_nodes;
    while (lo < hi) { int mid = (lo + hi) >> 1; if (batch[mid] < g + 1) lo = mid + 1; else hi = mid; }
    const int end = lo;

    const int t  = threadIdx.x;
    const int cu = t & 63;
    const int rp = t >> 6;
    const unsigned int* F = reinterpret_cast<const unsigned int*>(h);
    float a0 = 0.f, a1 = 0.f;
    for (int r = start + rp; r < end; r += 4) {
        unsigned int v = F[(size_t)r * 64 + cu];
        a0 += lo2f(v); a1 += hi2f(v);
    }
    __shared__ float s0[256], s1[256];
    s0[t] = a0; s1[t] = a1;
    __syncthreads();
    if (t < 64) {
        float r0 = s0[t] + s0[t + 64] + s0[t + 128] + s0[t + 192];
        float r1 = s1[t] + s1[t + 64] + s1[t + 128] + s1[t + 192];
        G[g * DIM + cu * 2]     = r0;
        G[g * DIM + cu * 2 + 1] = r1;
    }
}

// ---------------------------------------------------------------------------
// head (separate, parallel — round-6 design; fused 1-block version was 122us)
// ---------------------------------------------------------------------------
__global__ __launch_bounds__(256)
void head1_kernel(const float* __restrict__ G,
                  const float* __restrict__ W,
                  const float* __restrict__ b,
                  float* __restrict__ G2)
{
    int o = blockIdx.x * 256 + threadIdx.x;   // 64 blocks
    int r = o >> 7, c = o & 127;
    float acc = b[c];
    #pragma unroll 4
    for (int k = 0; k < DIM; ++k)
        acc = fmaf(G[r * DIM + k], W[k * DIM + c], acc);
    G2[o] = fmaxf(acc, 0.f);
}

__global__ __launch_bounds__(256)
void head2_kernel(const float* __restrict__ G2,
                  const float* __restrict__ W,
                  const float* __restrict__ b,
                  float* __restrict__ out)
{
    int o = threadIdx.x;
    int r = o >> 1, c = o & 1;
    float acc = b[c];
    #pragma unroll 4
    for (int k = 0; k < DIM; ++k)
        acc = fmaf(G2[r * DIM + k], W[k * 2 + c], acc);
    out[o] = acc;
}

// ---------------------------------------------------------------------------
extern "C" void kernel_launch(void* const* d_in, const int* in_sizes, int n_in,
                              void* d_out, int out_size, void* d_ws, size_t ws_size,
                              hipStream_t stream)
{
    const float* x    = (const float*)d_in[0];
    const int*   ei   = (const int*)d_in[1];
    const int*   src  = ei;
    const int*   dst  = ei + N_EDGES;
    const int*   batch= (const int*)d_in[2];
    const float* w1_1 = (const float*)d_in[3];
    const float* b1_1 = (const float*)d_in[4];
    const float* bn1g = (const float*)d_in[5];
    const float* bn1b = (const float*)d_in[6];
    const float* bn1m = (const float*)d_in[7];
    const float* bn1v = (const float*)d_in[8];
    const float* w1_2 = (const float*)d_in[9];
    const float* b1_2 = (const float*)d_in[10];
    const float* w2_1 = (const float*)d_in[11];
    const float* b2_1 = (const float*)d_in[12];
    const float* bn2g = (const float*)d_in[13];
    const float* bn2b = (const float*)d_in[14];
    const float* bn2m = (const float*)d_in[15];
    const float* bn2v = (const float*)d_in[16];
    const float* w2_2 = (const float*)d_in[17];
    const float* b2_2 = (const float*)d_in[18];
    const float* lin1w= (const float*)d_in[19];
    const float* lin1b= (const float*)d_in[20];
    const float* lin2w= (const float*)d_in[21];
    const float* lin2b= (const float*)d_in[22];

    const size_t NBE = (size_t)N_NODES * DIM;      // 6.4M
    __hip_bfloat16* xb = (__hip_bfloat16*)d_ws;    // NBE bf16
    __hip_bfloat16* Ab = xb + NBE;                 // NBE bf16 (agg)
    __hip_bfloat16* Hb = Ab + NBE;                 // NBE bf16 (mlp out)
    __hip_bfloat16* Wt = Hb + NBE;                 // 4 * 16384 bf16
    float* G  = (float*)(Wt + 4 * 16384);
    float* G2 = G + NUM_GRAPHS * DIM;
    int* rowptr = (int*)(G2 + NUM_GRAPHS * DIM);   // N_NODES+1
    int* bhist  = rowptr + N_NODES + 2;            // NBUCK
    int* bofs   = bhist + NBUCK;                   // NBUCK+1
    int* bcur   = bofs + NBUCK + 1;                // NBUCK
    unsigned int* bedge = (unsigned int*)(bcur + NBUCK + 1);     // N_EDGES
    unsigned short* elist = (unsigned short*)(bedge + N_EDGES);  // N_EDGES

    const int gather_grid = N_NODES / 4;               // 12500
    const int mlp_grid    = (N_NODES + 63) / 64;       // 782

    // ---- fused setup + bucketed CSR build ----
    setup_kernel<<<XGRID + WGRID + 1, 256, 0, stream>>>(
        x, xb, w1_1, w1_2, w2_1, w2_2, Wt, bhist);
    bhist_kernel<<<NTILE, 256, 0, stream>>>(dst, bhist);
    bscan_kernel<<<1, 512, 0, stream>>>(bhist, bofs, bcur);
    bscatter_kernel<<<NTILE, 512, 0, stream>>>(src, dst, bcur, bedge);
    bcsr_kernel<<<NBUCK, 256, 0, stream>>>(bedge, bofs, rowptr, elist);

    // ---- conv1 ----
    gather_agg_kernel<<<gather_grid, 256, 0, stream>>>(xb, rowptr, elist, Ab);
    mlp_kernel<<<mlp_grid, 256, 0, stream>>>(
        Ab, Wt, Wt + 16384, b1_1, bn1g, bn1b, bn1m, bn1v, b1_2, Hb, N_NODES);

    // ---- conv2 ----
    gather_agg_kernel<<<gather_grid, 256, 0, stream>>>(Hb, rowptr, elist, Ab);
    mlp_kernel<<<mlp_grid, 256, 0, stream>>>(
        Ab, Wt + 2 * 16384, Wt + 3 * 16384, b2_1, bn2g, bn2b, bn2m, bn2v, b2_2, Hb, N_NODES);

    // ---- pool + head ----
    pool_kernel<<<NUM_GRAPHS, 256, 0, stream>>>(Hb, batch, G, N_NODES);
    head1_kernel<<<64, 256, 0, stream>>>(G, lin1w, lin1b, G2);
    head2_kernel<<<1, 256, 0, stream>>>(G2, lin2w, lin2b, (float*)d_out);
}

// Round 9
// 164.547 us; speedup vs baseline: 1.8732x; 1.2375x over previous
//
#include <hip/hip_runtime.h>
#include <hip/hip_bf16.h>

#define N_NODES 50000
#define N_EDGES 800000
#define DIM 128
#define NUM_GRAPHS 128
#define BN_EPS 1e-5f

constexpr int BK     = 7;                               // nodes-per-bucket log2
constexpr int NBUCK  = (N_NODES + 127) >> BK;           // 391
constexpr int TILE   = 4096;                            // edges per bscatter block
constexpr int NTILE  = (N_EDGES + TILE - 1) / TILE;     // 196

constexpr int XGRID  = 6250;                            // convert-x blocks
constexpr int WGRID  = 256;                             // convert-wt blocks

typedef __attribute__((ext_vector_type(8))) short short8;
typedef __attribute__((ext_vector_type(4))) float f32x4;

__device__ __forceinline__ unsigned short f2bu(float v)
{
    __hip_bfloat16 h = __float2bfloat16(v);
    unsigned short u;
    __builtin_memcpy(&u, &h, 2);
    return u;
}
__device__ __forceinline__ float lo2f(unsigned int v)
{
    return __builtin_bit_cast(float, v << 16);
}
__device__ __forceinline__ float hi2f(unsigned int v)
{
    return __builtin_bit_cast(float, v & 0xffff0000u);
}
__device__ __forceinline__ float b2f(unsigned short u)
{
    return __builtin_bit_cast(float, ((unsigned int)u) << 16);
}

// ---------------------------------------------------------------------------
// fused setup: convert x -> bf16, transposed bf16 weights, zero bhist + G
// ---------------------------------------------------------------------------
__global__ __launch_bounds__(256)
void setup_kernel(const float* __restrict__ x, __hip_bfloat16* __restrict__ xb,
                  const float* __restrict__ w0, const float* __restrict__ w1,
                  const float* __restrict__ w2, const float* __restrict__ w3,
                  __hip_bfloat16* __restrict__ wt, int* __restrict__ bhist,
                  float* __restrict__ G)
{
    int b = blockIdx.x;
    int t = threadIdx.x;
    if (b < XGRID) {
        size_t i = ((size_t)b * 256 + t) * 4;
        float4 v = *reinterpret_cast<const float4*>(x + i);
        uint2 o;
        o.x = (unsigned int)f2bu(v.x) | ((unsigned int)f2bu(v.y) << 16);
        o.y = (unsigned int)f2bu(v.z) | ((unsigned int)f2bu(v.w) << 16);
        *reinterpret_cast<uint2*>(reinterpret_cast<unsigned short*>(xb) + i) = o;
    } else if (b < XGRID + WGRID) {
        int o = (b - XGRID) * 256 + t;            // 65536
        int m = o >> 14, idx = o & 16383;
        const float* W = (m == 0) ? w0 : (m == 1) ? w1 : (m == 2) ? w2 : w3;
        int n = idx >> 7, k = idx & 127;
        wt[o] = __float2bfloat16(W[k * 128 + n]);
    } else {
        for (int i = t; i < NBUCK; i += 256) bhist[i] = 0;
        for (int i = t; i < NUM_GRAPHS * DIM; i += 256) G[i] = 0.f;
    }
}

// ---------------------------------------------------------------------------
// Bucketed CSR build (single-writer output regions; verified round 6)
// ---------------------------------------------------------------------------
__global__ __launch_bounds__(256)
void bhist_kernel(const int* __restrict__ dst, int* __restrict__ bhist)
{
    __shared__ int h[NBUCK];
    int t = threadIdx.x;
    for (int i = t; i < NBUCK; i += 256) h[i] = 0;
    __syncthreads();
    int e0 = blockIdx.x * TILE;
    for (int i = t; i < TILE; i += 256) {
        int e = e0 + i;
        if (e < N_EDGES) atomicAdd(&h[dst[e] >> BK], 1);
    }
    __syncthreads();
    for (int i = t; i < NBUCK; i += 256)
        if (h[i]) atomicAdd(&bhist[i], h[i]);
}

__global__ __launch_bounds__(512)
void bscan_kernel(const int* __restrict__ bhist,
                  int* __restrict__ bofs, int* __restrict__ bcur)
{
    __shared__ int s[512];
    int t = threadIdx.x;
    int v = (t < NBUCK) ? bhist[t] : 0;
    s[t] = v;
    __syncthreads();
    for (int o = 1; o < 512; o <<= 1) {
        int a = (t >= o) ? s[t - o] : 0;
        __syncthreads();
        s[t] += a;
        __syncthreads();
    }
    if (t < NBUCK) {
        int ex = s[t] - v;
        bofs[t] = ex;
        bcur[t] = ex;
    }
    if (t == 0) bofs[NBUCK] = N_EDGES;
}

__global__ __launch_bounds__(512)
void bscatter_kernel(const int* __restrict__ src, const int* __restrict__ dst,
                     int* __restrict__ bcur, unsigned int* __restrict__ bedge)
{
    __shared__ int h[512];
    __shared__ int s[512];
    __shared__ int lofs[512];
    __shared__ int cur[512];
    __shared__ int gbase[512];
    __shared__ unsigned int stage[TILE];

    int t = threadIdx.x;
    h[t] = 0;
    __syncthreads();

    int e0 = blockIdx.x * TILE;
    for (int i = t; i < TILE; i += 512) {
        int e = e0 + i;
        if (e < N_EDGES) atomicAdd(&h[dst[e] >> BK], 1);
    }
    __syncthreads();

    int v = h[t];
    s[t] = v;
    __syncthreads();
    for (int o = 1; o < 512; o <<= 1) {
        int a = (t >= o) ? s[t - o] : 0;
        __syncthreads();
        s[t] += a;
        __syncthreads();
    }
    int excl = s[t] - v;
    lofs[t] = excl;
    cur[t]  = excl;
    if (t < NBUCK)
        gbase[t] = v ? atomicAdd(&bcur[t], v) : 0;
    __syncthreads();

    const int mtot = s[511];

    for (int i = t; i < TILE; i += 512) {
        int e = e0 + i;
        if (e < N_EDGES) {
            int d = dst[e];
            int b = d >> BK;
            int r = atomicAdd(&cur[b], 1);
            stage[r] = (unsigned int)src[e]
                     | ((unsigned int)(d & 127) << 16)
                     | ((unsigned int)b << 23);
        }
    }
    __syncthreads();

    for (int i = t; i < mtot; i += 512) {
        unsigned int w = stage[i];
        int b = (int)(w >> 23);
        bedge[gbase[b] + (i - lofs[b])] = w & 0x7fffffu;
    }
}

__global__ __launch_bounds__(256)
void bcsr_kernel(const unsigned int* __restrict__ bedge,
                 const int* __restrict__ bofs,
                 int* __restrict__ rowptr,
                 unsigned short* __restrict__ elist)
{
    __shared__ int h2[128];
    __shared__ int sc[128];
    __shared__ int cur[128];

    int b  = blockIdx.x;
    int t  = threadIdx.x;
    int e0 = bofs[b], e1 = bofs[b + 1];
    int m  = e1 - e0;

    if (t < 128) h2[t] = 0;
    __syncthreads();
    for (int i = t; i < m; i += 256)
        atomicAdd(&h2[(bedge[e0 + i] >> 16) & 127], 1);
    __syncthreads();

    if (t < 128) sc[t] = h2[t];
    __syncthreads();
    for (int o = 1; o < 128; o <<= 1) {
        int a = 0;
        if (t < 128 && t >= o) a = sc[t - o];
        __syncthreads();
        if (t < 128) sc[t] += a;
        __syncthreads();
    }
    if (t < 128) {
        int ex = sc[t] - h2[t];
        int node = (b << BK) + t;
        if (node < N_NODES) rowptr[node] = e0 + ex;
        cur[t] = ex;
    }
    if (b == 0 && t == 0) rowptr[N_NODES] = N_EDGES;
    __syncthreads();

    for (int i = t; i < m; i += 256) {
        unsigned int w = bedge[e0 + i];
        int n = (int)((w >> 16) & 127);
        int r = atomicAdd(&cur[n], 1);
        elist[e0 + r] = (unsigned short)(w & 0xffffu);
    }
}

// ---------------------------------------------------------------------------
// gather-aggregate (uint4 = 16B/lane). One WAVE per node.
//   lane = (edge-slot s = l>>4, chan-group g = l&15); unroll-16 main chunk
//   => 4 independent row loads in flight per lane (2x round-7 MLP).
// ---------------------------------------------------------------------------
__device__ __forceinline__ void accum8(float* acc, uint4 v)
{
    acc[0] += lo2f(v.x); acc[1] += hi2f(v.x);
    acc[2] += lo2f(v.y); acc[3] += hi2f(v.y);
    acc[4] += lo2f(v.z); acc[5] += hi2f(v.z);
    acc[6] += lo2f(v.w); acc[7] += hi2f(v.w);
}

__global__ __launch_bounds__(256)
void gather_agg_kernel(const __hip_bfloat16* __restrict__ feat,
                       const int* __restrict__ rowptr,
                       const unsigned short* __restrict__ elist,
                       __hip_bfloat16* __restrict__ out)
{
    const int node = blockIdx.x * 4 + (threadIdx.x >> 6);
    const int l = threadIdx.x & 63;
    const int g = l & 15;               // uint4 index in row (8 channels)
    const int s = l >> 4;               // edge slot 0..3
    const uint4* F = reinterpret_cast<const uint4*>(feat);

    int p = rowptr[node];
    const int e = rowptr[node + 1];

    float acc[8] = {};
    if (s == 0)
        accum8(acc, F[(size_t)node * 16 + g]);

    for (; p + 16 <= e; p += 16) {
        int i0 = elist[p + s];
        int i1 = elist[p + 4 + s];
        int i2 = elist[p + 8 + s];
        int i3 = elist[p + 12 + s];
        uint4 v0 = F[(size_t)i0 * 16 + g];
        uint4 v1 = F[(size_t)i1 * 16 + g];
        uint4 v2 = F[(size_t)i2 * 16 + g];
        uint4 v3 = F[(size_t)i3 * 16 + g];
        accum8(acc, v0);
        accum8(acc, v1);
        accum8(acc, v2);
        accum8(acc, v3);
    }
    if (p + 8 <= e) {
        int i0 = elist[p + s];
        int i1 = elist[p + 4 + s];
        uint4 v0 = F[(size_t)i0 * 16 + g];
        uint4 v1 = F[(size_t)i1 * 16 + g];
        accum8(acc, v0);
        accum8(acc, v1);
        p += 8;
    }
    if (p + 4 <= e) {
        int i0 = elist[p + s];
        uint4 v0 = F[(size_t)i0 * 16 + g];
        accum8(acc, v0);
        p += 4;
    }
    if (p + s < e) {
        int i0 = elist[p + s];
        uint4 v0 = F[(size_t)i0 * 16 + g];
        accum8(acc, v0);
    }

    #pragma unroll
    for (int j = 0; j < 8; ++j) {
        acc[j] += __shfl_xor(acc[j], 16);
        acc[j] += __shfl_xor(acc[j], 32);
    }

    if (s == 0) {
        uint4 o;
        o.x = (unsigned int)f2bu(acc[0]) | ((unsigned int)f2bu(acc[1]) << 16);
        o.y = (unsigned int)f2bu(acc[2]) | ((unsigned int)f2bu(acc[3]) << 16);
        o.z = (unsigned int)f2bu(acc[4]) | ((unsigned int)f2bu(acc[5]) << 16);
        o.w = (unsigned int)f2bu(acc[6]) | ((unsigned int)f2bu(acc[7]) << 16);
        reinterpret_cast<uint4*>(out)[(size_t)node * 16 + g] = o;
    }
}

// ---------------------------------------------------------------------------
// Fused GIN MLP: out = relu( relu(BN(A @ W1 + b1)) @ W2 + b2 )
// MFMA 16x16x32, W in LDS, t1 in LDS.
// POOL=1: instead of writing h2 to global, segment-sum the block's 64 rows
// by (sorted) batch id and atomicAdd f32 partials into G. (h2 feeds only
// global_add_pool, so the 12.8MB write + 12.8MB pool read are skipped.)
// ---------------------------------------------------------------------------
template<int POOL>
__global__ __launch_bounds__(256)
void mlp_kernel(const __hip_bfloat16* __restrict__ A,
                const __hip_bfloat16* __restrict__ W1t,
                const __hip_bfloat16* __restrict__ W2t,
                const float* __restrict__ b1,
                const float* __restrict__ bng, const float* __restrict__ bnb,
                const float* __restrict__ bnm, const float* __restrict__ bnv,
                const float* __restrict__ b2,
                __hip_bfloat16* __restrict__ out,
                const int* __restrict__ batch, float* __restrict__ G,
                int M)
{
    __shared__ __align__(16) short sW[128 * 136];   // 34.8 KB
    __shared__ __align__(16) short sT[64 * 136];    // 17.4 KB

    const int t    = threadIdx.x;
    const int w    = t >> 6;
    const int l    = t & 63;
    const int lr   = l & 15;
    const int lk   = (l >> 4) << 3;
    const int orow = (l >> 4) << 2;
    const int row0b = blockIdx.x * 64;
    const int row0 = row0b + w * 16;

    const short* w1s = reinterpret_cast<const short*>(W1t);
    #pragma unroll
    for (int i = t; i < 2048; i += 256) {
        int r = i >> 4, c8 = (i & 15) << 3;
        *reinterpret_cast<short8*>(&sW[r * 136 + c8]) =
            *reinterpret_cast<const short8*>(&w1s[r * 128 + c8]);
    }

    float sc1[8], sh1[8];
    #pragma unroll
    for (int ct = 0; ct < 8; ++ct) {
        int c = ct * 16 + lr;
        float s = bng[c] * rsqrtf(bnv[c] + BN_EPS);
        sc1[ct] = s;
        sh1[ct] = (b1[c] - bnm[c]) * s + bnb[c];
    }

    const short* Ab = reinterpret_cast<const short*>(A);
    const int arow = row0 + lr;
    short8 af[4];
    #pragma unroll
    for (int ks = 0; ks < 4; ++ks) {
        short8 z = {};
        af[ks] = (arow < M)
            ? *reinterpret_cast<const short8*>(Ab + (size_t)arow * DIM + ks * 32 + lk)
            : z;
    }

    __syncthreads();

    f32x4 acc[8] = {};
    #pragma unroll
    for (int ks = 0; ks < 4; ++ks) {
        #pragma unroll
        for (int ct = 0; ct < 8; ++ct) {
            short8 bf = *reinterpret_cast<const short8*>(
                &sW[(ct * 16 + lr) * 136 + ks * 32 + lk]);
            acc[ct] = __builtin_amdgcn_mfma_f32_16x16x32_bf16(af[ks], bf, acc[ct], 0, 0, 0);
        }
    }

    #pragma unroll
    for (int ct = 0; ct < 8; ++ct) {
        #pragma unroll
        for (int q = 0; q < 4; ++q) {
            float v = fmaxf(acc[ct][q] * sc1[ct] + sh1[ct], 0.f);
            sT[(w * 16 + orow + q) * 136 + ct * 16 + lr] = (short)f2bu(v);
        }
    }

    __syncthreads();
    const short* w2s = reinterpret_cast<const short*>(W2t);
    #pragma unroll
    for (int i = t; i < 2048; i += 256) {
        int r = i >> 4, c8 = (i & 15) << 3;
        *reinterpret_cast<short8*>(&sW[r * 136 + c8]) =
            *reinterpret_cast<const short8*>(&w2s[r * 128 + c8]);
    }
    __syncthreads();

    f32x4 acc2[8] = {};
    #pragma unroll
    for (int ks = 0; ks < 4; ++ks) {
        short8 tf = *reinterpret_cast<const short8*>(
            &sT[(w * 16 + lr) * 136 + ks * 32 + lk]);
        #pragma unroll
        for (int ct = 0; ct < 8; ++ct) {
            short8 bf = *reinterpret_cast<const short8*>(
                &sW[(ct * 16 + lr) * 136 + ks * 32 + lk]);
            acc2[ct] = __builtin_amdgcn_mfma_f32_16x16x32_bf16(tf, bf, acc2[ct], 0, 0, 0);
        }
    }

    if constexpr (!POOL) {
        #pragma unroll
        for (int ct = 0; ct < 8; ++ct) {
            float bi = b2[ct * 16 + lr];
            #pragma unroll
            for (int q = 0; q < 4; ++q) {
                int r = row0 + orow + q;
                if (r < M) {
                    float v = fmaxf(acc2[ct][q] + bi, 0.f);
                    out[(size_t)r * DIM + ct * 16 + lr] = __float2bfloat16(v);
                }
            }
        }
    } else {
        // write h2 rows to sT (each wave overwrites only its own 16 rows,
        // which only it read in GEMM2 -> in-wave ordering suffices)
        #pragma unroll
        for (int ct = 0; ct < 8; ++ct) {
            float bi = b2[ct * 16 + lr];
            #pragma unroll
            for (int q = 0; q < 4; ++q) {
                float v = fmaxf(acc2[ct][q] + bi, 0.f);
                sT[(w * 16 + orow + q) * 136 + ct * 16 + lr] = (short)f2bu(v);
            }
        }
        __syncthreads();
        // segment-sum rows by batch id: thread owns column c, 32-row half
        const int c  = t & 127;
        const int rh = t >> 7;
        float run = 0.f;
        int gcur = -1;
        for (int r = rh * 32; r < rh * 32 + 32; ++r) {
            int node = row0b + r;
            if (node >= M) break;
            int gb = batch[node];
            if (gb != gcur) {
                if (gcur >= 0 && run != 0.f) atomicAdd(&G[gcur * DIM + c], run);
                gcur = gb;
                run = 0.f;
            }
            run += b2f((unsigned short)sT[r * 136 + c]);
        }
        if (gcur >= 0 && run != 0.f) atomicAdd(&G[gcur * DIM + c], run);
    }
}

// ---------------------------------------------------------------------------
// head (separate, parallel — fused 1-block version was 122us in round 7)
// ---------------------------------------------------------------------------
__global__ __launch_bounds__(256)
void head1_kernel(const float* __restrict__ G,
                  const float* __restrict__ W,
                  const float* __restrict__ b,
                  float* __restrict__ G2)
{
    int o = blockIdx.x * 256 + threadIdx.x;   // 64 blocks
    int r = o >> 7, c = o & 127;
    float acc = b[c];
    #pragma unroll 4
    for (int k = 0; k < DIM; ++k)
        acc = fmaf(G[r * DIM + k], W[k * DIM + c], acc);
    G2[o] = fmaxf(acc, 0.f);
}

__global__ __launch_bounds__(256)
void head2_kernel(const float* __restrict__ G2,
                  const float* __restrict__ W,
                  const float* __restrict__ b,
                  float* __restrict__ out)
{
    int o = threadIdx.x;
    int r = o >> 1, c = o & 1;
    float acc = b[c];
    #pragma unroll 4
    for (int k = 0; k < DIM; ++k)
        acc = fmaf(G2[r * DIM + k], W[k * 2 + c], acc);
    out[o] = acc;
}

// ---------------------------------------------------------------------------
extern "C" void kernel_launch(void* const* d_in, const int* in_sizes, int n_in,
                              void* d_out, int out_size, void* d_ws, size_t ws_size,
                              hipStream_t stream)
{
    const float* x    = (const float*)d_in[0];
    const int*   ei   = (const int*)d_in[1];
    const int*   src  = ei;
    const int*   dst  = ei + N_EDGES;
    const int*   batch= (const int*)d_in[2];
    const float* w1_1 = (const float*)d_in[3];
    const float* b1_1 = (const float*)d_in[4];
    const float* bn1g = (const float*)d_in[5];
    const float* bn1b = (const float*)d_in[6];
    const float* bn1m = (const float*)d_in[7];
    const float* bn1v = (const float*)d_in[8];
    const float* w1_2 = (const float*)d_in[9];
    const float* b1_2 = (const float*)d_in[10];
    const float* w2_1 = (const float*)d_in[11];
    const float* b2_1 = (const float*)d_in[12];
    const float* bn2g = (const float*)d_in[13];
    const float* bn2b = (const float*)d_in[14];
    const float* bn2m = (const float*)d_in[15];
    const float* bn2v = (const float*)d_in[16];
    const float* w2_2 = (const float*)d_in[17];
    const float* b2_2 = (const float*)d_in[18];
    const float* lin1w= (const float*)d_in[19];
    const float* lin1b= (const float*)d_in[20];
    const float* lin2w= (const float*)d_in[21];
    const float* lin2b= (const float*)d_in[22];

    const size_t NBE = (size_t)N_NODES * DIM;      // 6.4M
    __hip_bfloat16* xb = (__hip_bfloat16*)d_ws;    // NBE bf16
    __hip_bfloat16* Ab = xb + NBE;                 // NBE bf16 (agg)
    __hip_bfloat16* Hb = Ab + NBE;                 // NBE bf16 (mlp1 out)
    __hip_bfloat16* Wt = Hb + NBE;                 // 4 * 16384 bf16
    float* G  = (float*)(Wt + 4 * 16384);
    float* G2 = G + NUM_GRAPHS * DIM;
    int* rowptr = (int*)(G2 + NUM_GRAPHS * DIM);   // N_NODES+1
    int* bhist  = rowptr + N_NODES + 2;            // NBUCK
    int* bofs   = bhist + NBUCK;                   // NBUCK+1
    int* bcur   = bofs + NBUCK + 1;                // NBUCK
    unsigned int* bedge = (unsigned int*)(bcur + NBUCK + 1);     // N_EDGES
    unsigned short* elist = (unsigned short*)(bedge + N_EDGES);  // N_EDGES

    const int gather_grid = N_NODES / 4;               // 12500
    const int mlp_grid    = (N_NODES + 63) / 64;       // 782

    // ---- fused setup + bucketed CSR build ----
    setup_kernel<<<XGRID + WGRID + 1, 256, 0, stream>>>(
        x, xb, w1_1, w1_2, w2_1, w2_2, Wt, bhist, G);
    bhist_kernel<<<NTILE, 256, 0, stream>>>(dst, bhist);
    bscan_kernel<<<1, 512, 0, stream>>>(bhist, bofs, bcur);
    bscatter_kernel<<<NTILE, 512, 0, stream>>>(src, dst, bcur, bedge);
    bcsr_kernel<<<NBUCK, 256, 0, stream>>>(bedge, bofs, rowptr, elist);

    // ---- conv1 ----
    gather_agg_kernel<<<gather_grid, 256, 0, stream>>>(xb, rowptr, elist, Ab);
    mlp_kernel<0><<<mlp_grid, 256, 0, stream>>>(
        Ab, Wt, Wt + 16384, b1_1, bn1g, bn1b, bn1m, bn1v, b1_2, Hb,
        batch, G, N_NODES);

    // ---- conv2 (pool fused into MLP epilogue) ----
    gather_agg_kernel<<<gather_grid, 256, 0, stream>>>(Hb, rowptr, elist, Ab);
    mlp_kernel<1><<<mlp_grid, 256, 0, stream>>>(
        Ab, Wt + 2 * 16384, Wt + 3 * 16384, b2_1, bn2g, bn2b, bn2m, bn2v, b2_2,
        (__hip_bfloat16*)nullptr, batch, G, N_NODES);

    // ---- head ----
    head1_kernel<<<64, 256, 0, stream>>>(G, lin1w, lin1b, G2);
    head2_kernel<<<1, 256, 0, stream>>>(G2, lin2w, lin2b, (float*)d_out);
}

// Round 10
// 143.623 us; speedup vs baseline: 2.1461x; 1.1457x over previous
//
#include <hip/hip_runtime.h>
#include <hip/hip_bf16.h>

#define N_NODES 50000
#define N_EDGES 800000
#define DIM 128
#define NUM_GRAPHS 128
#define BN_EPS 1e-5f

constexpr int BK     = 7;                               // nodes-per-bucket log2
constexpr int NBUCK  = (N_NODES + 127) >> BK;           // 391
constexpr int TILE   = 4096;                            // edges per bscatter block
constexpr int NTILE  = (N_EDGES + TILE - 1) / TILE;     // 196
constexpr int CAP    = 3072;                            // bucket capacity (mean 2046, +22 sigma)

constexpr int XGRID  = 6250;                            // convert-x blocks
constexpr int WGRID  = 256;                             // convert-wt blocks

typedef __attribute__((ext_vector_type(8))) short short8;
typedef __attribute__((ext_vector_type(4))) float f32x4;

__device__ __forceinline__ unsigned short f2bu(float v)
{
    __hip_bfloat16 h = __float2bfloat16(v);
    unsigned short u;
    __builtin_memcpy(&u, &h, 2);
    return u;
}
__device__ __forceinline__ float lo2f(unsigned int v)
{
    return __builtin_bit_cast(float, v << 16);
}
__device__ __forceinline__ float hi2f(unsigned int v)
{
    return __builtin_bit_cast(float, v & 0xffff0000u);
}
__device__ __forceinline__ float b2f(unsigned short u)
{
    return __builtin_bit_cast(float, ((unsigned int)u) << 16);
}

// ---------------------------------------------------------------------------
// fused setup: convert x -> bf16, transposed bf16 weights, zero bcur + G
// ---------------------------------------------------------------------------
__global__ __launch_bounds__(256)
void setup_kernel(const float* __restrict__ x, __hip_bfloat16* __restrict__ xb,
                  const float* __restrict__ w0, const float* __restrict__ w1,
                  const float* __restrict__ w2, const float* __restrict__ w3,
                  __hip_bfloat16* __restrict__ wt, int* __restrict__ bcur,
                  float* __restrict__ G)
{
    int b = blockIdx.x;
    int t = threadIdx.x;
    if (b < XGRID) {
        size_t i = ((size_t)b * 256 + t) * 4;
        float4 v = *reinterpret_cast<const float4*>(x + i);
        uint2 o;
        o.x = (unsigned int)f2bu(v.x) | ((unsigned int)f2bu(v.y) << 16);
        o.y = (unsigned int)f2bu(v.z) | ((unsigned int)f2bu(v.w) << 16);
        *reinterpret_cast<uint2*>(reinterpret_cast<unsigned short*>(xb) + i) = o;
    } else if (b < XGRID + WGRID) {
        int o = (b - XGRID) * 256 + t;            // 65536
        int m = o >> 14, idx = o & 16383;
        const float* W = (m == 0) ? w0 : (m == 1) ? w1 : (m == 2) ? w2 : w3;
        int n = idx >> 7, k = idx & 127;
        wt[o] = __float2bfloat16(W[k * 128 + n]);
    } else {
        for (int i = t; i < NBUCK; i += 256) bcur[i] = 0;
        for (int i = t; i < NUM_GRAPHS * DIM; i += 256) G[i] = 0.f;
    }
}

// ---------------------------------------------------------------------------
// Bucketed edge scatter, FIXED-STRIDE buckets (no hist/scan pre-passes):
// tile -> LDS grouped by bucket -> one atomicAdd per (tile,bucket) reserves
// a contiguous within-bucket range -> coalesced single-writer emits.
//    packed edge word: src(16) | dstlow(7)<<16 | bucket(9)<<23
// ---------------------------------------------------------------------------
__global__ __launch_bounds__(512)
void bscatter_kernel(const int* __restrict__ src, const int* __restrict__ dst,
                     int* __restrict__ bcur, unsigned int* __restrict__ bedge)
{
    __shared__ int h[512];
    __shared__ int s[512];
    __shared__ int lofs[512];
    __shared__ int cur[512];
    __shared__ int gofs[512];
    __shared__ unsigned int stage[TILE];

    int t = threadIdx.x;
    h[t] = 0;
    __syncthreads();

    int e0 = blockIdx.x * TILE;
    for (int i = t; i < TILE; i += 512) {
        int e = e0 + i;
        if (e < N_EDGES) atomicAdd(&h[dst[e] >> BK], 1);
    }
    __syncthreads();

    int v = h[t];
    s[t] = v;
    __syncthreads();
    for (int o = 1; o < 512; o <<= 1) {
        int a = (t >= o) ? s[t - o] : 0;
        __syncthreads();
        s[t] += a;
        __syncthreads();
    }
    int excl = s[t] - v;
    lofs[t] = excl;
    cur[t]  = excl;
    if (t < NBUCK)
        gofs[t] = v ? atomicAdd(&bcur[t], v) : 0;
    __syncthreads();

    const int mtot = s[511];

    for (int i = t; i < TILE; i += 512) {
        int e = e0 + i;
        if (e < N_EDGES) {
            int d = dst[e];
            int b = d >> BK;
            int r = atomicAdd(&cur[b], 1);
            stage[r] = (unsigned int)src[e]
                     | ((unsigned int)(d & 127) << 16)
                     | ((unsigned int)b << 23);
        }
    }
    __syncthreads();

    for (int i = t; i < mtot; i += 512) {
        unsigned int w = stage[i];
        int b = (int)(w >> 23);
        int pos = gofs[b] + (i - lofs[b]);
        if (pos < CAP)                                  // overflow guard (never fires)
            bedge[(size_t)b * CAP + pos] = w & 0x7fffffu;
    }
}

// ---------------------------------------------------------------------------
// per-bucket CSR finalize: rowbeg/rowend + ushort elist (strided layout),
// all global writes block-private
// ---------------------------------------------------------------------------
__global__ __launch_bounds__(256)
void bcsr_kernel(const unsigned int* __restrict__ bedge,
                 const int* __restrict__ bcur,
                 int* __restrict__ rowbeg, int* __restrict__ rowend,
                 unsigned short* __restrict__ elist)
{
    __shared__ int h2[128];
    __shared__ int sc[128];
    __shared__ int cur[128];

    int b  = blockIdx.x;
    int t  = threadIdx.x;
    int m  = bcur[b];
    if (m > CAP) m = CAP;
    const int e0 = b * CAP;
    const unsigned int* be = bedge + (size_t)e0;

    if (t < 128) h2[t] = 0;
    __syncthreads();
    for (int i = t; i < m; i += 256)
        atomicAdd(&h2[(be[i] >> 16) & 127], 1);
    __syncthreads();

    if (t < 128) sc[t] = h2[t];
    __syncthreads();
    for (int o = 1; o < 128; o <<= 1) {
        int a = 0;
        if (t < 128 && t >= o) a = sc[t - o];
        __syncthreads();
        if (t < 128) sc[t] += a;
        __syncthreads();
    }
    if (t < 128) {
        int ex = sc[t] - h2[t];
        int node = (b << BK) + t;
        if (node < N_NODES) {
            rowbeg[node] = e0 + ex;
            rowend[node] = e0 + ex + h2[t];
        }
        cur[t] = ex;
    }
    __syncthreads();

    for (int i = t; i < m; i += 256) {
        unsigned int w = be[i];
        int n = (int)((w >> 16) & 127);
        int r = atomicAdd(&cur[n], 1);
        elist[e0 + r] = (unsigned short)(w & 0xffffu);
    }
}

// ---------------------------------------------------------------------------
// gather-aggregate (uint4 = 16B/lane). One WAVE per node (verified round 9):
//   lane = (edge-slot s = l>>4, chan-group g = l&15); unroll-16 main chunk;
//   cross-slot reduce via __shfl_xor(16/32); self term in slot 0.
// ---------------------------------------------------------------------------
__device__ __forceinline__ void accum8(float* acc, uint4 v)
{
    acc[0] += lo2f(v.x); acc[1] += hi2f(v.x);
    acc[2] += lo2f(v.y); acc[3] += hi2f(v.y);
    acc[4] += lo2f(v.z); acc[5] += hi2f(v.z);
    acc[6] += lo2f(v.w); acc[7] += hi2f(v.w);
}

__global__ __launch_bounds__(256)
void gather_agg_kernel(const __hip_bfloat16* __restrict__ feat,
                       const int* __restrict__ rowbeg,
                       const int* __restrict__ rowend,
                       const unsigned short* __restrict__ elist,
                       __hip_bfloat16* __restrict__ out)
{
    const int node = blockIdx.x * 4 + (threadIdx.x >> 6);
    const int l = threadIdx.x & 63;
    const int g = l & 15;               // uint4 index in row (8 channels)
    const int s = l >> 4;               // edge slot 0..3
    const uint4* F = reinterpret_cast<const uint4*>(feat);

    int p = rowbeg[node];
    const int e = rowend[node];

    float acc[8] = {};
    if (s == 0)
        accum8(acc, F[(size_t)node * 16 + g]);

    for (; p + 16 <= e; p += 16) {
        int i0 = elist[p + s];
        int i1 = elist[p + 4 + s];
        int i2 = elist[p + 8 + s];
        int i3 = elist[p + 12 + s];
        uint4 v0 = F[(size_t)i0 * 16 + g];
        uint4 v1 = F[(size_t)i1 * 16 + g];
        uint4 v2 = F[(size_t)i2 * 16 + g];
        uint4 v3 = F[(size_t)i3 * 16 + g];
        accum8(acc, v0);
        accum8(acc, v1);
        accum8(acc, v2);
        accum8(acc, v3);
    }
    if (p + 8 <= e) {
        int i0 = elist[p + s];
        int i1 = elist[p + 4 + s];
        uint4 v0 = F[(size_t)i0 * 16 + g];
        uint4 v1 = F[(size_t)i1 * 16 + g];
        accum8(acc, v0);
        accum8(acc, v1);
        p += 8;
    }
    if (p + 4 <= e) {
        int i0 = elist[p + s];
        uint4 v0 = F[(size_t)i0 * 16 + g];
        accum8(acc, v0);
        p += 4;
    }
    if (p + s < e) {
        int i0 = elist[p + s];
        uint4 v0 = F[(size_t)i0 * 16 + g];
        accum8(acc, v0);
    }

    #pragma unroll
    for (int j = 0; j < 8; ++j) {
        acc[j] += __shfl_xor(acc[j], 16);
        acc[j] += __shfl_xor(acc[j], 32);
    }

    if (s == 0) {
        uint4 o;
        o.x = (unsigned int)f2bu(acc[0]) | ((unsigned int)f2bu(acc[1]) << 16);
        o.y = (unsigned int)f2bu(acc[2]) | ((unsigned int)f2bu(acc[3]) << 16);
        o.z = (unsigned int)f2bu(acc[4]) | ((unsigned int)f2bu(acc[5]) << 16);
        o.w = (unsigned int)f2bu(acc[6]) | ((unsigned int)f2bu(acc[7]) << 16);
        reinterpret_cast<uint4*>(out)[(size_t)node * 16 + g] = o;
    }
}

// ---------------------------------------------------------------------------
// Fused GIN MLP: out = relu( relu(BN(A @ W1 + b1)) @ W2 + b2 )
// MFMA 16x16x32, W in LDS, t1 in LDS.
// POOL=1: segment-sum the block's 64 h2 rows by sorted batch id, atomicAdd
// f32 partials into G (h2 never hits global).
// ---------------------------------------------------------------------------
template<int POOL>
__global__ __launch_bounds__(256)
void mlp_kernel(const __hip_bfloat16* __restrict__ A,
                const __hip_bfloat16* __restrict__ W1t,
                const __hip_bfloat16* __restrict__ W2t,
                const float* __restrict__ b1,
                const float* __restrict__ bng, const float* __restrict__ bnb,
                const float* __restrict__ bnm, const float* __restrict__ bnv,
                const float* __restrict__ b2,
                __hip_bfloat16* __restrict__ out,
                const int* __restrict__ batch, float* __restrict__ G,
                int M)
{
    __shared__ __align__(16) short sW[128 * 136];   // 34.8 KB
    __shared__ __align__(16) short sT[64 * 136];    // 17.4 KB

    const int t    = threadIdx.x;
    const int w    = t >> 6;
    const int l    = t & 63;
    const int lr   = l & 15;
    const int lk   = (l >> 4) << 3;
    const int orow = (l >> 4) << 2;
    const int row0b = blockIdx.x * 64;
    const int row0 = row0b + w * 16;

    const short* w1s = reinterpret_cast<const short*>(W1t);
    #pragma unroll
    for (int i = t; i < 2048; i += 256) {
        int r = i >> 4, c8 = (i & 15) << 3;
        *reinterpret_cast<short8*>(&sW[r * 136 + c8]) =
            *reinterpret_cast<const short8*>(&w1s[r * 128 + c8]);
    }

    float sc1[8], sh1[8];
    #pragma unroll
    for (int ct = 0; ct < 8; ++ct) {
        int c = ct * 16 + lr;
        float s = bng[c] * rsqrtf(bnv[c] + BN_EPS);
        sc1[ct] = s;
        sh1[ct] = (b1[c] - bnm[c]) * s + bnb[c];
    }

    const short* Ab = reinterpret_cast<const short*>(A);
    const int arow = row0 + lr;
    short8 af[4];
    #pragma unroll
    for (int ks = 0; ks < 4; ++ks) {
        short8 z = {};
        af[ks] = (arow < M)
            ? *reinterpret_cast<const short8*>(Ab + (size_t)arow * DIM + ks * 32 + lk)
            : z;
    }

    __syncthreads();

    f32x4 acc[8] = {};
    #pragma unroll
    for (int ks = 0; ks < 4; ++ks) {
        #pragma unroll
        for (int ct = 0; ct < 8; ++ct) {
            short8 bf = *reinterpret_cast<const short8*>(
                &sW[(ct * 16 + lr) * 136 + ks * 32 + lk]);
            acc[ct] = __builtin_amdgcn_mfma_f32_16x16x32_bf16(af[ks], bf, acc[ct], 0, 0, 0);
        }
    }

    #pragma unroll
    for (int ct = 0; ct < 8; ++ct) {
        #pragma unroll
        for (int q = 0; q < 4; ++q) {
            float v = fmaxf(acc[ct][q] * sc1[ct] + sh1[ct], 0.f);
            sT[(w * 16 + orow + q) * 136 + ct * 16 + lr] = (short)f2bu(v);
        }
    }

    __syncthreads();
    const short* w2s = reinterpret_cast<const short*>(W2t);
    #pragma unroll
    for (int i = t; i < 2048; i += 256) {
        int r = i >> 4, c8 = (i & 15) << 3;
        *reinterpret_cast<short8*>(&sW[r * 136 + c8]) =
            *reinterpret_cast<const short8*>(&w2s[r * 128 + c8]);
    }
    __syncthreads();

    f32x4 acc2[8] = {};
    #pragma unroll
    for (int ks = 0; ks < 4; ++ks) {
        short8 tf = *reinterpret_cast<const short8*>(
            &sT[(w * 16 + lr) * 136 + ks * 32 + lk]);
        #pragma unroll
        for (int ct = 0; ct < 8; ++ct) {
            short8 bf = *reinterpret_cast<const short8*>(
                &sW[(ct * 16 + lr) * 136 + ks * 32 + lk]);
            acc2[ct] = __builtin_amdgcn_mfma_f32_16x16x32_bf16(tf, bf, acc2[ct], 0, 0, 0);
        }
    }

    if constexpr (!POOL) {
        #pragma unroll
        for (int ct = 0; ct < 8; ++ct) {
            float bi = b2[ct * 16 + lr];
            #pragma unroll
            for (int q = 0; q < 4; ++q) {
                int r = row0 + orow + q;
                if (r < M) {
                    float v = fmaxf(acc2[ct][q] + bi, 0.f);
                    out[(size_t)r * DIM + ct * 16 + lr] = __float2bfloat16(v);
                }
            }
        }
    } else {
        #pragma unroll
        for (int ct = 0; ct < 8; ++ct) {
            float bi = b2[ct * 16 + lr];
            #pragma unroll
            for (int q = 0; q < 4; ++q) {
                float v = fmaxf(acc2[ct][q] + bi, 0.f);
                sT[(w * 16 + orow + q) * 136 + ct * 16 + lr] = (short)f2bu(v);
            }
        }
        __syncthreads();
        const int c  = t & 127;
        const int rh = t >> 7;
        float run = 0.f;
        int gcur = -1;
        for (int r = rh * 32; r < rh * 32 + 32; ++r) {
            int node = row0b + r;
            if (node >= M) break;
            int gb = batch[node];
            if (gb != gcur) {
                if (gcur >= 0 && run != 0.f) atomicAdd(&G[gcur * DIM + c], run);
                gcur = gb;
                run = 0.f;
            }
            run += b2f((unsigned short)sT[r * 136 + c]);
        }
        if (gcur >= 0 && run != 0.f) atomicAdd(&G[gcur * DIM + c], run);
    }
}

// ---------------------------------------------------------------------------
// fused head, PARALLEL: one block per graph (128 blocks x 128 threads).
// Block r: thread c computes G2[r][c] (G row broadcast from LDS, w1
// coalesced), then LDS tree-reduce for the 2 outputs.
// ---------------------------------------------------------------------------
__global__ __launch_bounds__(128)
void head_kernel(const float* __restrict__ G,
                 const float* __restrict__ w1, const float* __restrict__ b1f,
                 const float* __restrict__ w2, const float* __restrict__ b2f,
                 float* __restrict__ out)
{
    __shared__ float sg[DIM];
    __shared__ float r0[DIM], r1[DIM];
    const int r = blockIdx.x;
    const int c = threadIdx.x;

    sg[c] = G[r * DIM + c];
    __syncthreads();

    float a = b1f[c];
    #pragma unroll 8
    for (int k = 0; k < DIM; ++k)
        a = fmaf(sg[k], w1[k * DIM + c], a);
    float g2 = fmaxf(a, 0.f);
    r0[c] = g2 * w2[c * 2];
    r1[c] = g2 * w2[c * 2 + 1];
    __syncthreads();

    for (int off = 64; off > 0; off >>= 1) {
        if (c < off) { r0[c] += r0[c + off]; r1[c] += r1[c + off]; }
        __syncthreads();
    }
    if (c == 0) {
        out[r * 2]     = r0[0] + b2f[0];
        out[r * 2 + 1] = r1[0] + b2f[1];
    }
}

// ---------------------------------------------------------------------------
extern "C" void kernel_launch(void* const* d_in, const int* in_sizes, int n_in,
                              void* d_out, int out_size, void* d_ws, size_t ws_size,
                              hipStream_t stream)
{
    const float* x    = (const float*)d_in[0];
    const int*   ei   = (const int*)d_in[1];
    const int*   src  = ei;
    const int*   dst  = ei + N_EDGES;
    const int*   batch= (const int*)d_in[2];
    const float* w1_1 = (const float*)d_in[3];
    const float* b1_1 = (const float*)d_in[4];
    const float* bn1g = (const float*)d_in[5];
    const float* bn1b = (const float*)d_in[6];
    const float* bn1m = (const float*)d_in[7];
    const float* bn1v = (const float*)d_in[8];
    const float* w1_2 = (const float*)d_in[9];
    const float* b1_2 = (const float*)d_in[10];
    const float* w2_1 = (const float*)d_in[11];
    const float* b2_1 = (const float*)d_in[12];
    const float* bn2g = (const float*)d_in[13];
    const float* bn2b = (const float*)d_in[14];
    const float* bn2m = (const float*)d_in[15];
    const float* bn2v = (const float*)d_in[16];
    const float* w2_2 = (const float*)d_in[17];
    const float* b2_2 = (const float*)d_in[18];
    const float* lin1w= (const float*)d_in[19];
    const float* lin1b= (const float*)d_in[20];
    const float* lin2w= (const float*)d_in[21];
    const float* lin2b= (const float*)d_in[22];

    const size_t NBE = (size_t)N_NODES * DIM;      // 6.4M
    __hip_bfloat16* xb = (__hip_bfloat16*)d_ws;    // NBE bf16
    __hip_bfloat16* Ab = xb + NBE;                 // NBE bf16 (agg)
    __hip_bfloat16* Hb = Ab + NBE;                 // NBE bf16 (mlp1 out)
    __hip_bfloat16* Wt = Hb + NBE;                 // 4 * 16384 bf16
    float* G  = (float*)(Wt + 4 * 16384);
    int* rowbeg = (int*)(G + NUM_GRAPHS * DIM);    // N_NODES
    int* rowend = rowbeg + N_NODES;                // N_NODES
    int* bcur   = rowend + N_NODES;                // NBUCK
    unsigned int* bedge = (unsigned int*)(bcur + NBUCK + 1);       // NBUCK*CAP
    unsigned short* elist = (unsigned short*)(bedge + (size_t)NBUCK * CAP);

    const int gather_grid = N_NODES / 4;               // 12500
    const int mlp_grid    = (N_NODES + 63) / 64;       // 782

    // ---- fused setup + fixed-stride bucket scatter + CSR finalize ----
    setup_kernel<<<XGRID + WGRID + 1, 256, 0, stream>>>(
        x, xb, w1_1, w1_2, w2_1, w2_2, Wt, bcur, G);
    bscatter_kernel<<<NTILE, 512, 0, stream>>>(src, dst, bcur, bedge);
    bcsr_kernel<<<NBUCK, 256, 0, stream>>>(bedge, bcur, rowbeg, rowend, elist);

    // ---- conv1 ----
    gather_agg_kernel<<<gather_grid, 256, 0, stream>>>(xb, rowbeg, rowend, elist, Ab);
    mlp_kernel<0><<<mlp_grid, 256, 0, stream>>>(
        Ab, Wt, Wt + 16384, b1_1, bn1g, bn1b, bn1m, bn1v, b1_2, Hb,
        batch, G, N_NODES);

    // ---- conv2 (pool fused into MLP epilogue) ----
    gather_agg_kernel<<<gather_grid, 256, 0, stream>>>(Hb, rowbeg, rowend, elist, Ab);
    mlp_kernel<1><<<mlp_grid, 256, 0, stream>>>(
        Ab, Wt + 2 * 16384, Wt + 3 * 16384, b2_1, bn2g, bn2b, bn2m, bn2v, b2_2,
        (__hip_bfloat16*)nullptr, batch, G, N_NODES);

    // ---- head (single parallel kernel) ----
    head_kernel<<<NUM_GRAPHS, 128, 0, stream>>>(
        G, lin1w, lin1b, lin2w, lin2b, (float*)d_out);
}

// Round 11
// 140.076 us; speedup vs baseline: 2.2005x; 1.0253x over previous
//
#include <hip/hip_runtime.h>
#include <hip/hip_bf16.h>

#define N_NODES 50000
#define N_EDGES 800000
#define DIM 128
#define NUM_GRAPHS 128
#define BN_EPS 1e-5f

constexpr int BK     = 7;                               // nodes-per-bucket log2
constexpr int NBUCK  = (N_NODES + 127) >> BK;           // 391
constexpr int TILE   = 4096;                            // edges per bscatter block
constexpr int NTILE  = (N_EDGES + TILE - 1) / TILE;     // 196
constexpr int CAP    = 4096;                            // bucket capacity incl. padding
constexpr int NPAD   = N_NODES;                         // zero-row index for padding

constexpr int XGRID  = 6250;                            // convert-x blocks
constexpr int WGRID  = 256;                             // convert-wt blocks

typedef __attribute__((ext_vector_type(8))) short short8;
typedef __attribute__((ext_vector_type(4))) float f32x4;

__device__ __forceinline__ unsigned short f2bu(float v)
{
    __hip_bfloat16 h = __float2bfloat16(v);
    unsigned short u;
    __builtin_memcpy(&u, &h, 2);
    return u;
}
__device__ __forceinline__ float lo2f(unsigned int v)
{
    return __builtin_bit_cast(float, v << 16);
}
__device__ __forceinline__ float hi2f(unsigned int v)
{
    return __builtin_bit_cast(float, v & 0xffff0000u);
}
__device__ __forceinline__ float b2f(unsigned short u)
{
    return __builtin_bit_cast(float, ((unsigned int)u) << 16);
}

// ---------------------------------------------------------------------------
// fused setup: convert x -> bf16, transposed bf16 weights, zero bcur + G +
// the NPAD zero-rows of xb and Hb (read by padded gather entries)
// ---------------------------------------------------------------------------
__global__ __launch_bounds__(256)
void setup_kernel(const float* __restrict__ x, __hip_bfloat16* __restrict__ xb,
                  const float* __restrict__ w0, const float* __restrict__ w1,
                  const float* __restrict__ w2, const float* __restrict__ w3,
                  __hip_bfloat16* __restrict__ wt, int* __restrict__ bcur,
                  float* __restrict__ G, __hip_bfloat16* __restrict__ Hb)
{
    int b = blockIdx.x;
    int t = threadIdx.x;
    if (b < XGRID) {
        size_t i = ((size_t)b * 256 + t) * 4;
        float4 v = *reinterpret_cast<const float4*>(x + i);
        uint2 o;
        o.x = (unsigned int)f2bu(v.x) | ((unsigned int)f2bu(v.y) << 16);
        o.y = (unsigned int)f2bu(v.z) | ((unsigned int)f2bu(v.w) << 16);
        *reinterpret_cast<uint2*>(reinterpret_cast<unsigned short*>(xb) + i) = o;
    } else if (b < XGRID + WGRID) {
        int o = (b - XGRID) * 256 + t;            // 65536
        int m = o >> 14, idx = o & 16383;
        const float* W = (m == 0) ? w0 : (m == 1) ? w1 : (m == 2) ? w2 : w3;
        int n = idx >> 7, k = idx & 127;
        wt[o] = __float2bfloat16(W[k * 128 + n]);
    } else {
        for (int i = t; i < NBUCK; i += 256) bcur[i] = 0;
        for (int i = t; i < NUM_GRAPHS * DIM; i += 256) G[i] = 0.f;
        if (t < 128) {
            xb[(size_t)NPAD * DIM + t] = __float2bfloat16(0.f);
            Hb[(size_t)NPAD * DIM + t] = __float2bfloat16(0.f);
        }
    }
}

// ---------------------------------------------------------------------------
// Bucketed edge scatter, FIXED-STRIDE buckets (no hist/scan pre-passes):
// tile -> LDS grouped by bucket -> one atomicAdd per (tile,bucket) reserves
// a contiguous within-bucket range -> coalesced single-writer emits.
//    packed edge word: src(16) | dstlow(7)<<16 | bucket(9)<<23
// ---------------------------------------------------------------------------
__global__ __launch_bounds__(512)
void bscatter_kernel(const int* __restrict__ src, const int* __restrict__ dst,
                     int* __restrict__ bcur, unsigned int* __restrict__ bedge)
{
    __shared__ int h[512];
    __shared__ int s[512];
    __shared__ int lofs[512];
    __shared__ int cur[512];
    __shared__ int gofs[512];
    __shared__ unsigned int stage[TILE];

    int t = threadIdx.x;
    h[t] = 0;
    __syncthreads();

    int e0 = blockIdx.x * TILE;
    for (int i = t; i < TILE; i += 512) {
        int e = e0 + i;
        if (e < N_EDGES) atomicAdd(&h[dst[e] >> BK], 1);
    }
    __syncthreads();

    int v = h[t];
    s[t] = v;
    __syncthreads();
    for (int o = 1; o < 512; o <<= 1) {
        int a = (t >= o) ? s[t - o] : 0;
        __syncthreads();
        s[t] += a;
        __syncthreads();
    }
    int excl = s[t] - v;
    lofs[t] = excl;
    cur[t]  = excl;
    if (t < NBUCK)
        gofs[t] = v ? atomicAdd(&bcur[t], v) : 0;
    __syncthreads();

    const int mtot = s[511];

    for (int i = t; i < TILE; i += 512) {
        int e = e0 + i;
        if (e < N_EDGES) {
            int d = dst[e];
            int b = d >> BK;
            int r = atomicAdd(&cur[b], 1);
            stage[r] = (unsigned int)src[e]
                     | ((unsigned int)(d & 127) << 16)
                     | ((unsigned int)b << 23);
        }
    }
    __syncthreads();

    for (int i = t; i < mtot; i += 512) {
        unsigned int w = stage[i];
        int b = (int)(w >> 23);
        int pos = gofs[b] + (i - lofs[b]);
        if (pos < CAP)                                  // overflow guard (never fires)
            bedge[(size_t)b * CAP + pos] = w & 0x7fffffu;
    }
}

// ---------------------------------------------------------------------------
// per-bucket CSR finalize: per-node ranges PADDED to x16 with NPAD zero-row
// entries -> gather's inner loop is uniform 16-edge chunks, no tails.
// rowbeg/rowend + ushort elist (strided layout), all writes block-private.
// ---------------------------------------------------------------------------
__global__ __launch_bounds__(256)
void bcsr_kernel(const unsigned int* __restrict__ bedge,
                 const int* __restrict__ bcur,
                 int* __restrict__ rowbeg, int* __restrict__ rowend,
                 unsigned short* __restrict__ elist)
{
    __shared__ int h2[128];     // real counts
    __shared__ int sc[128];     // scan of padded counts
    __shared__ int cur[128];

    int b  = blockIdx.x;
    int t  = threadIdx.x;
    int m  = bcur[b];
    if (m > CAP) m = CAP;
    const int e0 = b * CAP;
    const unsigned int* be = bedge + (size_t)e0;

    if (t < 128) h2[t] = 0;
    __syncthreads();
    for (int i = t; i < m; i += 256)
        atomicAdd(&h2[(be[i] >> 16) & 127], 1);
    __syncthreads();

    int pc = 0;
    if (t < 128) {
        pc = (h2[t] + 15) & ~15;          // padded count
        sc[t] = pc;
    }
    __syncthreads();
    for (int o = 1; o < 128; o <<= 1) {
        int a = 0;
        if (t < 128 && t >= o) a = sc[t - o];
        __syncthreads();
        if (t < 128) sc[t] += a;
        __syncthreads();
    }
    if (t < 128) {
        int ex = sc[t] - pc;
        int node = (b << BK) + t;
        if (node < N_NODES) {
            rowbeg[node] = e0 + ex;
            rowend[node] = e0 + ex + pc;
        }
        cur[t] = ex;
        // pad tail [cnt, pc) with NPAD (<= 15 entries, block-private region)
        int cnt = h2[t];
        for (int i = ex + cnt; i < ex + pc && i < CAP; ++i)
            elist[e0 + i] = (unsigned short)NPAD;
    }
    __syncthreads();

    for (int i = t; i < m; i += 256) {
        unsigned int w = be[i];
        int n = (int)((w >> 16) & 127);
        int r = atomicAdd(&cur[n], 1);
        if (r < CAP)
            elist[e0 + r] = (unsigned short)(w & 0xffffu);
    }
}

// ---------------------------------------------------------------------------
// gather-aggregate (uint4 = 16B/lane). One WAVE per node.
//   lane = (edge-slot s = l>>4, chan-group g = l&15).
//   Edge lists padded to x16 with NPAD zero-rows -> uniform chunks only:
//   32-edge chunks (8 loads in flight/lane) then 16-edge chunks (4 loads).
//   Cross-slot reduce via __shfl_xor(16/32); self term in slot 0.
// ---------------------------------------------------------------------------
__device__ __forceinline__ void accum8(float* acc, uint4 v)
{
    acc[0] += lo2f(v.x); acc[1] += hi2f(v.x);
    acc[2] += lo2f(v.y); acc[3] += hi2f(v.y);
    acc[4] += lo2f(v.z); acc[5] += hi2f(v.z);
    acc[6] += lo2f(v.w); acc[7] += hi2f(v.w);
}

__global__ __launch_bounds__(256)
void gather_agg_kernel(const __hip_bfloat16* __restrict__ feat,
                       const int* __restrict__ rowbeg,
                       const int* __restrict__ rowend,
                       const unsigned short* __restrict__ elist,
                       __hip_bfloat16* __restrict__ out)
{
    const int node = blockIdx.x * 4 + (threadIdx.x >> 6);
    const int l = threadIdx.x & 63;
    const int g = l & 15;               // uint4 index in row (8 channels)
    const int s = l >> 4;               // edge slot 0..3
    const uint4* F = reinterpret_cast<const uint4*>(feat);

    int p = rowbeg[node];
    const int e = rowend[node];

    float acc[8] = {};
    if (s == 0)
        accum8(acc, F[(size_t)node * 16 + g]);

    for (; p + 32 <= e; p += 32) {
        int i0 = elist[p + s];
        int i1 = elist[p + 4 + s];
        int i2 = elist[p + 8 + s];
        int i3 = elist[p + 12 + s];
        int i4 = elist[p + 16 + s];
        int i5 = elist[p + 20 + s];
        int i6 = elist[p + 24 + s];
        int i7 = elist[p + 28 + s];
        uint4 v0 = F[(size_t)i0 * 16 + g];
        uint4 v1 = F[(size_t)i1 * 16 + g];
        uint4 v2 = F[(size_t)i2 * 16 + g];
        uint4 v3 = F[(size_t)i3 * 16 + g];
        uint4 v4 = F[(size_t)i4 * 16 + g];
        uint4 v5 = F[(size_t)i5 * 16 + g];
        uint4 v6 = F[(size_t)i6 * 16 + g];
        uint4 v7 = F[(size_t)i7 * 16 + g];
        accum8(acc, v0);
        accum8(acc, v1);
        accum8(acc, v2);
        accum8(acc, v3);
        accum8(acc, v4);
        accum8(acc, v5);
        accum8(acc, v6);
        accum8(acc, v7);
    }
    if (p < e) {                        // exactly one 16-chunk remains
        int i0 = elist[p + s];
        int i1 = elist[p + 4 + s];
        int i2 = elist[p + 8 + s];
        int i3 = elist[p + 12 + s];
        uint4 v0 = F[(size_t)i0 * 16 + g];
        uint4 v1 = F[(size_t)i1 * 16 + g];
        uint4 v2 = F[(size_t)i2 * 16 + g];
        uint4 v3 = F[(size_t)i3 * 16 + g];
        accum8(acc, v0);
        accum8(acc, v1);
        accum8(acc, v2);
        accum8(acc, v3);
    }

    #pragma unroll
    for (int j = 0; j < 8; ++j) {
        acc[j] += __shfl_xor(acc[j], 16);
        acc[j] += __shfl_xor(acc[j], 32);
    }

    if (s == 0) {
        uint4 o;
        o.x = (unsigned int)f2bu(acc[0]) | ((unsigned int)f2bu(acc[1]) << 16);
        o.y = (unsigned int)f2bu(acc[2]) | ((unsigned int)f2bu(acc[3]) << 16);
        o.z = (unsigned int)f2bu(acc[4]) | ((unsigned int)f2bu(acc[5]) << 16);
        o.w = (unsigned int)f2bu(acc[6]) | ((unsigned int)f2bu(acc[7]) << 16);
        reinterpret_cast<uint4*>(out)[(size_t)node * 16 + g] = o;
    }
}

// ---------------------------------------------------------------------------
// Fused GIN MLP: out = relu( relu(BN(A @ W1 + b1)) @ W2 + b2 )
// MFMA 16x16x32, W in LDS, t1 in LDS.
// POOL=1: segment-sum the block's 64 h2 rows by sorted batch id, atomicAdd
// f32 partials into G (h2 never hits global).
// ---------------------------------------------------------------------------
template<int POOL>
__global__ __launch_bounds__(256)
void mlp_kernel(const __hip_bfloat16* __restrict__ A,
                const __hip_bfloat16* __restrict__ W1t,
                const __hip_bfloat16* __restrict__ W2t,
                const float* __restrict__ b1,
                const float* __restrict__ bng, const float* __restrict__ bnb,
                const float* __restrict__ bnm, const float* __restrict__ bnv,
                const float* __restrict__ b2,
                __hip_bfloat16* __restrict__ out,
                const int* __restrict__ batch, float* __restrict__ G,
                int M)
{
    __shared__ __align__(16) short sW[128 * 136];   // 34.8 KB
    __shared__ __align__(16) short sT[64 * 136];    // 17.4 KB

    const int t    = threadIdx.x;
    const int w    = t >> 6;
    const int l    = t & 63;
    const int lr   = l & 15;
    const int lk   = (l >> 4) << 3;
    const int orow = (l >> 4) << 2;
    const int row0b = blockIdx.x * 64;
    const int row0 = row0b + w * 16;

    const short* w1s = reinterpret_cast<const short*>(W1t);
    #pragma unroll
    for (int i = t; i < 2048; i += 256) {
        int r = i >> 4, c8 = (i & 15) << 3;
        *reinterpret_cast<short8*>(&sW[r * 136 + c8]) =
            *reinterpret_cast<const short8*>(&w1s[r * 128 + c8]);
    }

    float sc1[8], sh1[8];
    #pragma unroll
    for (int ct = 0; ct < 8; ++ct) {
        int c = ct * 16 + lr;
        float s = bng[c] * rsqrtf(bnv[c] + BN_EPS);
        sc1[ct] = s;
        sh1[ct] = (b1[c] - bnm[c]) * s + bnb[c];
    }

    const short* Ab = reinterpret_cast<const short*>(A);
    const int arow = row0 + lr;
    short8 af[4];
    #pragma unroll
    for (int ks = 0; ks < 4; ++ks) {
        short8 z = {};
        af[ks] = (arow < M)
            ? *reinterpret_cast<const short8*>(Ab + (size_t)arow * DIM + ks * 32 + lk)
            : z;
    }

    __syncthreads();

    f32x4 acc[8] = {};
    #pragma unroll
    for (int ks = 0; ks < 4; ++ks) {
        #pragma unroll
        for (int ct = 0; ct < 8; ++ct) {
            short8 bf = *reinterpret_cast<const short8*>(
                &sW[(ct * 16 + lr) * 136 + ks * 32 + lk]);
            acc[ct] = __builtin_amdgcn_mfma_f32_16x16x32_bf16(af[ks], bf, acc[ct], 0, 0, 0);
        }
    }

    #pragma unroll
    for (int ct = 0; ct < 8; ++ct) {
        #pragma unroll
        for (int q = 0; q < 4; ++q) {
            float v = fmaxf(acc[ct][q] * sc1[ct] + sh1[ct], 0.f);
            sT[(w * 16 + orow + q) * 136 + ct * 16 + lr] = (short)f2bu(v);
        }
    }

    __syncthreads();
    const short* w2s = reinterpret_cast<const short*>(W2t);
    #pragma unroll
    for (int i = t; i < 2048; i += 256) {
        int r = i >> 4, c8 = (i & 15) << 3;
        *reinterpret_cast<short8*>(&sW[r * 136 + c8]) =
            *reinterpret_cast<const short8*>(&w2s[r * 128 + c8]);
    }
    __syncthreads();

    f32x4 acc2[8] = {};
    #pragma unroll
    for (int ks = 0; ks < 4; ++ks) {
        short8 tf = *reinterpret_cast<const short8*>(
            &sT[(w * 16 + lr) * 136 + ks * 32 + lk]);
        #pragma unroll
        for (int ct = 0; ct < 8; ++ct) {
            short8 bf = *reinterpret_cast<const short8*>(
                &sW[(ct * 16 + lr) * 136 + ks * 32 + lk]);
            acc2[ct] = __builtin_amdgcn_mfma_f32_16x16x32_bf16(tf, bf, acc2[ct], 0, 0, 0);
        }
    }

    if constexpr (!POOL) {
        #pragma unroll
        for (int ct = 0; ct < 8; ++ct) {
            float bi = b2[ct * 16 + lr];
            #pragma unroll
            for (int q = 0; q < 4; ++q) {
                int r = row0 + orow + q;
                if (r < M) {
                    float v = fmaxf(acc2[ct][q] + bi, 0.f);
                    out[(size_t)r * DIM + ct * 16 + lr] = __float2bfloat16(v);
                }
            }
        }
    } else {
        #pragma unroll
        for (int ct = 0; ct < 8; ++ct) {
            float bi = b2[ct * 16 + lr];
            #pragma unroll
            for (int q = 0; q < 4; ++q) {
                float v = fmaxf(acc2[ct][q] + bi, 0.f);
                sT[(w * 16 + orow + q) * 136 + ct * 16 + lr] = (short)f2bu(v);
            }
        }
        __syncthreads();
        const int c  = t & 127;
        const int rh = t >> 7;
        float run = 0.f;
        int gcur = -1;
        for (int r = rh * 32; r < rh * 32 + 32; ++r) {
            int node = row0b + r;
            if (node >= M) break;
            int gb = batch[node];
            if (gb != gcur) {
                if (gcur >= 0 && run != 0.f) atomicAdd(&G[gcur * DIM + c], run);
                gcur = gb;
                run = 0.f;
            }
            run += b2f((unsigned short)sT[r * 136 + c]);
        }
        if (gcur >= 0 && run != 0.f) atomicAdd(&G[gcur * DIM + c], run);
    }
}

// ---------------------------------------------------------------------------
// fused head, PARALLEL: one block per graph (128 blocks x 128 threads).
// ---------------------------------------------------------------------------
__global__ __launch_bounds__(128)
void head_kernel(const float* __restrict__ G,
                 const float* __restrict__ w1, const float* __restrict__ b1f,
                 const float* __restrict__ w2, const float* __restrict__ b2f,
                 float* __restrict__ out)
{
    __shared__ float sg[DIM];
    __shared__ float r0[DIM], r1[DIM];
    const int r = blockIdx.x;
    const int c = threadIdx.x;

    sg[c] = G[r * DIM + c];
    __syncthreads();

    float a = b1f[c];
    #pragma unroll 8
    for (int k = 0; k < DIM; ++k)
        a = fmaf(sg[k], w1[k * DIM + c], a);
    float g2 = fmaxf(a, 0.f);
    r0[c] = g2 * w2[c * 2];
    r1[c] = g2 * w2[c * 2 + 1];
    __syncthreads();

    for (int off = 64; off > 0; off >>= 1) {
        if (c < off) { r0[c] += r0[c + off]; r1[c] += r1[c + off]; }
        __syncthreads();
    }
    if (c == 0) {
        out[r * 2]     = r0[0] + b2f[0];
        out[r * 2 + 1] = r1[0] + b2f[1];
    }
}

// ---------------------------------------------------------------------------
extern "C" void kernel_launch(void* const* d_in, const int* in_sizes, int n_in,
                              void* d_out, int out_size, void* d_ws, size_t ws_size,
                              hipStream_t stream)
{
    const float* x    = (const float*)d_in[0];
    const int*   ei   = (const int*)d_in[1];
    const int*   src  = ei;
    const int*   dst  = ei + N_EDGES;
    const int*   batch= (const int*)d_in[2];
    const float* w1_1 = (const float*)d_in[3];
    const float* b1_1 = (const float*)d_in[4];
    const float* bn1g = (const float*)d_in[5];
    const float* bn1b = (const float*)d_in[6];
    const float* bn1m = (const float*)d_in[7];
    const float* bn1v = (const float*)d_in[8];
    const float* w1_2 = (const float*)d_in[9];
    const float* b1_2 = (const float*)d_in[10];
    const float* w2_1 = (const float*)d_in[11];
    const float* b2_1 = (const float*)d_in[12];
    const float* bn2g = (const float*)d_in[13];
    const float* bn2b = (const float*)d_in[14];
    const float* bn2m = (const float*)d_in[15];
    const float* bn2v = (const float*)d_in[16];
    const float* w2_2 = (const float*)d_in[17];
    const float* b2_2 = (const float*)d_in[18];
    const float* lin1w= (const float*)d_in[19];
    const float* lin1b= (const float*)d_in[20];
    const float* lin2w= (const float*)d_in[21];
    const float* lin2b= (const float*)d_in[22];

    const size_t NBE  = (size_t)N_NODES * DIM;     // 6.4M
    const size_t NBEP = NBE + DIM;                 // + zero pad row
    __hip_bfloat16* xb = (__hip_bfloat16*)d_ws;    // NBEP bf16
    __hip_bfloat16* Ab = xb + NBEP;                // NBE bf16 (agg)
    __hip_bfloat16* Hb = Ab + NBE;                 // NBEP bf16 (mlp1 out)
    __hip_bfloat16* Wt = Hb + NBEP;                // 4 * 16384 bf16
    float* G  = (float*)(Wt + 4 * 16384);
    int* rowbeg = (int*)(G + NUM_GRAPHS * DIM);    // N_NODES
    int* rowend = rowbeg + N_NODES;                // N_NODES
    int* bcur   = rowend + N_NODES;                // NBUCK
    unsigned int* bedge = (unsigned int*)(bcur + NBUCK + 1);       // NBUCK*CAP
    unsigned short* elist = (unsigned short*)(bedge + (size_t)NBUCK * CAP);

    const int gather_grid = N_NODES / 4;               // 12500
    const int mlp_grid    = (N_NODES + 63) / 64;       // 782

    // ---- fused setup + fixed-stride bucket scatter + padded CSR finalize ----
    setup_kernel<<<XGRID + WGRID + 1, 256, 0, stream>>>(
        x, xb, w1_1, w1_2, w2_1, w2_2, Wt, bcur, G, Hb);
    bscatter_kernel<<<NTILE, 512, 0, stream>>>(src, dst, bcur, bedge);
    bcsr_kernel<<<NBUCK, 256, 0, stream>>>(bedge, bcur, rowbeg, rowend, elist);

    // ---- conv1 ----
    gather_agg_kernel<<<gather_grid, 256, 0, stream>>>(xb, rowbeg, rowend, elist, Ab);
    mlp_kernel<0><<<mlp_grid, 256, 0, stream>>>(
        Ab, Wt, Wt + 16384, b1_1, bn1g, bn1b, bn1m, bn1v, b1_2, Hb,
        batch, G, N_NODES);

    // ---- conv2 (pool fused into MLP epilogue) ----
    gather_agg_kernel<<<gather_grid, 256, 0, stream>>>(Hb, rowbeg, rowend, elist, Ab);
    mlp_kernel<1><<<mlp_grid, 256, 0, stream>>>(
        Ab, Wt + 2 * 16384, Wt + 3 * 16384, b2_1, bn2g, bn2b, bn2m, bn2v, b2_2,
        (__hip_bfloat16*)nullptr, batch, G, N_NODES);

    // ---- head (single parallel kernel) ----
    head_kernel<<<NUM_GRAPHS, 128, 0, stream>>>(
        G, lin1w, lin1b, lin2w, lin2b, (float*)d_out);
}